// Round 6
// baseline (628.999 us; speedup 1.0000x reference)
//
#include <hip/hip_runtime.h>
#include <hip/hip_bf16.h>
#include <math.h>

// Problem constants (B=4, Cin=256, Cout=128, H=W=64)
#define NB 4
#define CI 256
#define CO 128
#define HW 4096

typedef __attribute__((ext_vector_type(8))) short s8v;   // 8 bf16 = 4 VGPRs (MFMA A/B frag)
typedef __attribute__((ext_vector_type(4))) short s4v;
typedef __attribute__((ext_vector_type(4))) float f4v;   // MFMA C/D frag

__device__ __forceinline__ unsigned short f2bf(float f){
    __hip_bfloat16 h = __float2bfloat16(f);   // RNE
    return *reinterpret_cast<unsigned short*>(&h);
}

// A&S 7.1.26 erf (max abs err 1.5e-7)
__device__ __forceinline__ float gelu_f(float x){
    float z  = x * 0.70710678118654752f;
    float az = fabsf(z);
    float tt = 1.f / (1.f + 0.3275911f * az);
    float poly = tt*(0.254829592f + tt*(-0.284496736f + tt*(1.421413741f +
                 tt*(-1.453152027f + tt*1.061405429f))));
    float erfv = 1.f - poly * __expf(-az*az);
    erfv = (z < 0.f) ? -erfv : erfv;
    return 0.5f * x * (1.f + erfv);
}

// ---------------- per-channel avg/max over HW ----------------
__global__ void k_rowstats(const float* __restrict__ x, float* __restrict__ avg, float* __restrict__ mx){
    int row = blockIdx.x;
    const float* p = x + (long long)row * HW;
    int t = threadIdx.x;
    float s = 0.f, m = -1e30f;
    for (int i = t; i < HW; i += 256){ float v = p[i]; s += v; m = fmaxf(m, v); }
    __shared__ float ss[256], sm[256];
    ss[t] = s; sm[t] = m; __syncthreads();
    for (int o = 128; o > 0; o >>= 1){
        if (t < o){ ss[t] += ss[t+o]; sm[t] = fmaxf(sm[t], sm[t+o]); }
        __syncthreads();
    }
    if (t == 0){ avg[row] = ss[0] / (float)HW; mx[row] = sm[0]; }
}

// ---------------- ChannelWeighting; also gp = avg*(1+s) ----------------
__global__ void k_cw(const float* __restrict__ avg, const float* __restrict__ mx,
                     const float* __restrict__ w1, const float* __restrict__ b1,
                     const float* __restrict__ lng, const float* __restrict__ lnb,
                     const float* __restrict__ w2, const float* __restrict__ b2,
                     float* __restrict__ sv, float* __restrict__ gp){
    int b = blockIdx.x, t = threadIdx.x;
    __shared__ float o_s[256];
    __shared__ float h_s[128];
    __shared__ float stat[2];
    float a = avg[b*256 + t];
    o_s[t] = fabsf(a - mx[b*256 + t]) * a;
    __syncthreads();
    if (t < 128){
        float h = b1[t];
        for (int i = 0; i < 256; i++) h += o_s[i] * w1[t*256 + i];
        h_s[t] = h;
    }
    __syncthreads();
    if (t == 0){
        float s = 0.f, s2 = 0.f;
        for (int j = 0; j < 128; j++){ s += h_s[j]; s2 += h_s[j]*h_s[j]; }
        float mean = s / 128.f;
        float var  = s2 / 128.f - mean*mean;
        stat[0] = mean; stat[1] = rsqrtf(var + 1e-5f);
    }
    __syncthreads();
    if (t < 128) h_s[t] = lng[t] * ((h_s[t] - stat[0]) * stat[1]) + lnb[t];
    __syncthreads();
    float z = b2[t];
    for (int j = 0; j < 128; j++) z += h_s[j] * w2[t*128 + j];
    float sig = 1.f / (1.f + __expf(-z));
    sv[b*256 + t] = sig;
    gp[b*256 + t] = a * (1.f + sig);
}

// ---------------- weight casts ----------------
__global__ void k_wcast(const float* __restrict__ in, unsigned short* __restrict__ out){
    int i = blockIdx.x*256 + threadIdx.x;
    out[i] = f2bf(in[i]);
}
// conv3 weights [O=256][I=256][9] f32 -> [tap][O][I] bf16
__global__ void k_w3(const float* __restrict__ in, unsigned short* __restrict__ out){
    int j = blockIdx.x*256 + threadIdx.x;
    int tap = j >> 16, rem = j & 65535, o = rem >> 8, ci = rem & 255;
    out[j] = f2bf(in[o*2304 + ci*9 + tap]);
}

// ---------------- x -> xT bf16 [b][HW][256] and xcT = bf16(x*(1+s)) ----------------
__global__ void k_xT(const float* __restrict__ x, const float* __restrict__ sv,
                     unsigned short* __restrict__ xT, unsigned short* __restrict__ xcT){
    int b = blockIdx.z, c0 = blockIdx.y*64, h0 = blockIdx.x*64;
    __shared__ unsigned short T1[64][66], T2[64][66];
    int t = threadIdx.x;
    int hl = t & 63, cs = t >> 6;
    #pragma unroll
    for (int r = 0; r < 16; r++){
        int c = cs*16 + r;
        float v = x[((long long)b*256 + c0 + c)*HW + h0 + hl];
        float sc = 1.f + sv[b*256 + c0 + c];
        T1[c][hl] = f2bf(v);
        T2[c][hl] = f2bf(v*sc);
    }
    __syncthreads();
    int cl = t & 63, hs = t >> 6;
    #pragma unroll
    for (int r = 0; r < 16; r++){
        int h = hs*16 + r;
        long long o = ((long long)b*HW + h0 + h)*256 + c0 + cl;
        xT[o]  = T1[cl][h];
        xcT[o] = T2[cl][h];
    }
}

// ============ 8-wave epilogue, N=32: LN(256ch)+GELU -> transposed bf16 ============
// acc[2][2]: (ms,ct,r) at p=ct*16+m, c=w*32+ms*16+q*4+r  (w=0..7)
__device__ __forceinline__ void ln_epi32(f4v acc[2][2],
        int b, int n0, int w, int lane, int m, int q, int t,
        const float* Gs, const float* Bts,
        float (*Psum)[32], float (*Psq)[32], float* Mn, float* Iv,
        unsigned short* __restrict__ outT, int outPitch, int colOff){
    float ls[2], ls2[2];
    #pragma unroll
    for (int ct = 0; ct < 2; ct++){
        float s = 0.f, s2 = 0.f;
        #pragma unroll
        for (int ms = 0; ms < 2; ms++)
            #pragma unroll
            for (int r = 0; r < 4; r++){ float v = acc[ms][ct][r]; s += v; s2 += v*v; }
        ls[ct] = s; ls2[ct] = s2;
    }
    #pragma unroll
    for (int ct = 0; ct < 2; ct++){
        ls[ct]  += __shfl_xor(ls[ct], 16);  ls[ct]  += __shfl_xor(ls[ct], 32);
        ls2[ct] += __shfl_xor(ls2[ct], 16); ls2[ct] += __shfl_xor(ls2[ct], 32);
    }
    if (lane < 16){
        #pragma unroll
        for (int ct = 0; ct < 2; ct++){ Psum[w][ct*16+lane] = ls[ct]; Psq[w][ct*16+lane] = ls2[ct]; }
    }
    __syncthreads();
    if (t < 32){
        float s = 0.f, s2 = 0.f;
        #pragma unroll
        for (int ww = 0; ww < 8; ww++){ s += Psum[ww][t]; s2 += Psq[ww][t]; }
        float mean = s * (1.f/256.f);
        Mn[t] = mean;
        Iv[t] = rsqrtf(s2*(1.f/256.f) - mean*mean + 1e-6f);
    }
    __syncthreads();
    #pragma unroll
    for (int ct = 0; ct < 2; ct++){
        int p = ct*16 + m;
        float mean = Mn[p], inv = Iv[p];
        long long rowb = ((long long)b*HW + n0 + p)*outPitch + colOff;
        #pragma unroll
        for (int ms = 0; ms < 2; ms++){
            s4v o4;
            #pragma unroll
            for (int r = 0; r < 4; r++){
                int c = w*32 + ms*16 + q*4 + r;
                float h = Gs[c]*((acc[ms][ct][r] - mean)*inv) + Bts[c];
                o4[r] = (short)f2bf(gelu_f(h));
            }
            *(s4v*)(outT + rowb + w*32 + ms*16 + q*4) = o4;
        }
    }
}

// ---------------- fused 1x1-conv (MFMA) + LN + GELU, 512 thr, N=32, Kstage=64 ----------------
__global__ __launch_bounds__(512)
void k_branch1(const unsigned short* __restrict__ A, int K,
               const unsigned short* __restrict__ BT,
               const float* __restrict__ g, const float* __restrict__ beta,
               unsigned short* __restrict__ outT, int outPitch, int colOff){
    int b = blockIdx.y, n0 = blockIdx.x*32;
    const unsigned short* BTb = BT + (long long)b*HW*K;
    __shared__ unsigned short As[256][72];
    __shared__ unsigned short Bs[32][72];
    __shared__ float Psum[8][32], Psq[8][32], Mn[32], Iv[32];
    __shared__ float Gs[256], Bts[256];
    int t = threadIdx.x, w = t>>6, lane = t&63, m = lane&15, q = lane>>4;
    if (t < 256){ Gs[t] = g[t]; Bts[t] = beta[t]; }
    f4v acc[2][2];
    #pragma unroll
    for (int ms = 0; ms < 2; ms++)
        #pragma unroll
        for (int ct = 0; ct < 2; ct++){ f4v z = {0.f,0.f,0.f,0.f}; acc[ms][ct] = z; }
    for (int k0 = 0; k0 < K; k0 += 64){
        __syncthreads();
        {   int r = t>>1, half = t&1;
            const uint4* src = (const uint4*)(A + (long long)r*K + k0 + half*32);
            uint4* dst = (uint4*)&As[r][half*32];
            dst[0]=src[0]; dst[1]=src[1]; dst[2]=src[2]; dst[3]=src[3];
        }
        {   int n = t>>4, ch = t&15;
            *(uint2*)&Bs[n][ch*4] = *(const uint2*)(BTb + (long long)(n0+n)*K + k0 + ch*4);
        }
        __syncthreads();
        #pragma unroll
        for (int ks = 0; ks < 2; ks++){
            s8v bfr[2];
            #pragma unroll
            for (int ct = 0; ct < 2; ct++) bfr[ct] = *(const s8v*)&Bs[ct*16+m][q*8+ks*32];
            #pragma unroll
            for (int ms = 0; ms < 2; ms++){
                s8v afr = *(const s8v*)&As[w*32 + ms*16 + m][q*8+ks*32];
                #pragma unroll
                for (int ct = 0; ct < 2; ct++)
                    acc[ms][ct] = __builtin_amdgcn_mfma_f32_16x16x32_bf16(afr, bfr[ct], acc[ms][ct], 0,0,0);
            }
        }
    }
    __syncthreads();
    ln_epi32(acc, b, n0, w, lane, m, q, t, Gs, Bts, Psum, Psq, Mn, Iv, outT, outPitch, colOff);
}

// ---------------- fused 3x3 dilated conv (MFMA) + LN + GELU, 512 thr, N=32, Kstage=64 ----------------
__global__ __launch_bounds__(512)
void k_branch3(const unsigned short* __restrict__ Wb,
               const unsigned short* __restrict__ BT, int d,
               const float* __restrict__ g, const float* __restrict__ beta,
               unsigned short* __restrict__ outT, int colOff){
    int b = blockIdx.y;
    int y = blockIdx.x >> 1, x0 = (blockIdx.x & 1)*32;
    int n0 = y*64 + x0;
    const unsigned short* BTb = BT + (long long)b*HW*256;
    __shared__ unsigned short As[256][72];
    __shared__ unsigned short Bs[32][72];
    __shared__ float Psum[8][32], Psq[8][32], Mn[32], Iv[32];
    __shared__ float Gs[256], Bts[256];
    int t = threadIdx.x, w = t>>6, lane = t&63, m = lane&15, q = lane>>4;
    if (t < 256){ Gs[t] = g[t]; Bts[t] = beta[t]; }
    f4v acc[2][2];
    #pragma unroll
    for (int ms = 0; ms < 2; ms++)
        #pragma unroll
        for (int ct = 0; ct < 2; ct++){ f4v z = {0.f,0.f,0.f,0.f}; acc[ms][ct] = z; }
    for (int tap = 0; tap < 9; tap++){
        int dy = tap/3 - 1, dx = tap%3 - 1;
        int ys = y + dy*d;
        bool yok = (unsigned)ys < 64u;
        const unsigned short* wtap = Wb + (long long)tap*65536;
        for (int kc = 0; kc < 4; kc++){
            int ci0 = kc*64;
            __syncthreads();
            {   int r = t>>1, half = t&1;
                const uint4* src = (const uint4*)(wtap + (long long)r*256 + ci0 + half*32);
                uint4* dst = (uint4*)&As[r][half*32];
                dst[0]=src[0]; dst[1]=src[1]; dst[2]=src[2]; dst[3]=src[3];
            }
            {   int n = t>>4, ch = t&15;
                int xs = x0 + n + dx*d;
                uint2 v = {0u,0u};
                if (yok && (unsigned)xs < 64u)
                    v = *(const uint2*)(BTb + (long long)(ys*64+xs)*256 + ci0 + ch*4);
                *(uint2*)&Bs[n][ch*4] = v;
            }
            __syncthreads();
            #pragma unroll
            for (int ks = 0; ks < 2; ks++){
                s8v bfr[2];
                #pragma unroll
                for (int ct = 0; ct < 2; ct++) bfr[ct] = *(const s8v*)&Bs[ct*16+m][q*8+ks*32];
                #pragma unroll
                for (int ms = 0; ms < 2; ms++){
                    s8v afr = *(const s8v*)&As[w*32 + ms*16 + m][q*8+ks*32];
                    #pragma unroll
                    for (int ct = 0; ct < 2; ct++)
                        acc[ms][ct] = __builtin_amdgcn_mfma_f32_16x16x32_bf16(afr, bfr[ct], acc[ms][ct], 0,0,0);
                }
            }
        }
    }
    __syncthreads();
    ln_epi32(acc, b, n0, w, lane, m, q, t, Gs, Bts, Psum, Psq, Mn, Iv, outT, 1280, colOff);
}

// ---------------- conv1 (M=128) MFMA, 256 thr, N=32, Kstage=64 ----------------
__global__ __launch_bounds__(256)
void k_conv1m(const unsigned short* __restrict__ A,      // [128][256] bf16
              const unsigned short* __restrict__ BT,     // [b][HW][256] bf16
              const float* __restrict__ bias,
              unsigned short* __restrict__ outT,         // [b][HW][128] bf16
              unsigned short* __restrict__ outC,         // [b][128][HW] bf16 or null
              float* __restrict__ outF){                 // [b][128][HW] f32 or null
    int b = blockIdx.y, n0 = blockIdx.x*32;
    const unsigned short* BTb = BT + (long long)b*HW*256;
    __shared__ unsigned short As[128][72];
    __shared__ unsigned short Bs[32][72];
    int t = threadIdx.x, w = t>>6, lane = t&63, m = lane&15, q = lane>>4;
    f4v acc[2][2];
    #pragma unroll
    for (int ms = 0; ms < 2; ms++)
        #pragma unroll
        for (int ct = 0; ct < 2; ct++){ f4v z = {0.f,0.f,0.f,0.f}; acc[ms][ct] = z; }
    for (int k0 = 0; k0 < 256; k0 += 64){
        __syncthreads();
        {   int r = t>>1, half = t&1;
            const uint4* src = (const uint4*)(A + (long long)r*256 + k0 + half*32);
            uint4* dst = (uint4*)&As[r][half*32];
            dst[0]=src[0]; dst[1]=src[1]; dst[2]=src[2]; dst[3]=src[3];
        }
        {   int n = t>>3, ch = t&7;
            *(uint4*)&Bs[n][ch*8] = *(const uint4*)(BTb + (long long)(n0+n)*256 + k0 + ch*8);
        }
        __syncthreads();
        #pragma unroll
        for (int ks = 0; ks < 2; ks++){
            s8v bfr[2];
            #pragma unroll
            for (int ct = 0; ct < 2; ct++) bfr[ct] = *(const s8v*)&Bs[ct*16+m][q*8+ks*32];
            #pragma unroll
            for (int ms = 0; ms < 2; ms++){
                s8v afr = *(const s8v*)&As[w*32 + ms*16 + m][q*8+ks*32];
                #pragma unroll
                for (int ct = 0; ct < 2; ct++)
                    acc[ms][ct] = __builtin_amdgcn_mfma_f32_16x16x32_bf16(afr, bfr[ct], acc[ms][ct], 0,0,0);
            }
        }
    }
    #pragma unroll
    for (int ct = 0; ct < 2; ct++){
        int p = n0 + ct*16 + m;
        #pragma unroll
        for (int ms = 0; ms < 2; ms++){
            s4v o4;
            float vals[4];
            #pragma unroll
            for (int r = 0; r < 4; r++){
                int c = w*32 + ms*16 + q*4 + r;
                vals[r] = acc[ms][ct][r] + bias[c];
                o4[r] = (short)f2bf(vals[r]);
            }
            *(s4v*)(outT + ((long long)b*HW + p)*128 + w*32 + ms*16 + q*4) = o4;
            if (outC){
                #pragma unroll
                for (int r = 0; r < 4; r++){
                    int c = w*32 + ms*16 + q*4 + r;
                    outC[((long long)b*128 + c)*HW + p] = (unsigned short)o4[r];
                }
            }
            if (outF){
                #pragma unroll
                for (int r = 0; r < 4; r++){
                    int c = w*32 + ms*16 + q*4 + r;
                    outF[((long long)b*128 + c)*HW + p] = vals[r];
                }
            }
        }
    }
}

// ---------------- conv2 (M=256, K=128) MFMA -> out f32 + bias, N=32 ----------------
__global__ __launch_bounds__(256)
void k_gemm_out(const unsigned short* __restrict__ A,    // [256][128] bf16
                const unsigned short* __restrict__ BT,   // [b][HW][128] bf16
                const float* __restrict__ bias,
                float* __restrict__ out){
    int b = blockIdx.y, n0 = blockIdx.x*32;
    const unsigned short* BTb = BT + (long long)b*HW*128;
    __shared__ unsigned short As[256][72];
    __shared__ unsigned short Bs[32][72];
    int t = threadIdx.x, w = t>>6, lane = t&63, m = lane&15, q = lane>>4;
    f4v acc[4][2];
    #pragma unroll
    for (int ms = 0; ms < 4; ms++)
        #pragma unroll
        for (int ct = 0; ct < 2; ct++){ f4v z = {0.f,0.f,0.f,0.f}; acc[ms][ct] = z; }
    for (int k0 = 0; k0 < 128; k0 += 64){
        __syncthreads();
        {   // FIX(R5 bug): full 64 shorts (8 uint4) per row, one row per thread
            const uint4* src = (const uint4*)(A + (long long)t*128 + k0);
            uint4* dst = (uint4*)&As[t][0];
            #pragma unroll
            for (int i = 0; i < 8; i++) dst[i] = src[i];
        }
        {   int n = t>>3, ch = t&7;
            *(uint4*)&Bs[n][ch*8] = *(const uint4*)(BTb + (long long)(n0+n)*128 + k0 + ch*8);
        }
        __syncthreads();
        #pragma unroll
        for (int ks = 0; ks < 2; ks++){
            s8v bfr[2];
            #pragma unroll
            for (int ct = 0; ct < 2; ct++) bfr[ct] = *(const s8v*)&Bs[ct*16+m][q*8+ks*32];
            #pragma unroll
            for (int ms = 0; ms < 4; ms++){
                s8v afr = *(const s8v*)&As[w*64 + ms*16 + m][q*8+ks*32];
                #pragma unroll
                for (int ct = 0; ct < 2; ct++)
                    acc[ms][ct] = __builtin_amdgcn_mfma_f32_16x16x32_bf16(afr, bfr[ct], acc[ms][ct], 0,0,0);
            }
        }
    }
    #pragma unroll
    for (int ct = 0; ct < 2; ct++){
        int p = n0 + ct*16 + m;
        #pragma unroll
        for (int ms = 0; ms < 4; ms++)
            #pragma unroll
            for (int r = 0; r < 4; r++){
                int c = w*64 + ms*16 + q*4 + r;
                out[((long long)b*256 + c)*HW + p] = acc[ms][ct][r] + bias[c];
            }
    }
}

// ---------------- pooled branch ----------------
__global__ void k_pool(const float* __restrict__ gp, const float* __restrict__ w,
                       const float* __restrict__ g, const float* __restrict__ bta,
                       float* __restrict__ bp){
    int b = blockIdx.x, t = threadIdx.x;
    __shared__ float z_s[256];
    __shared__ float stat[2];
    float z = 0.f;
    for (int c = 0; c < 256; c++) z += gp[b*256 + c] * w[t*256 + c];
    z_s[t] = z;
    __syncthreads();
    if (t == 0){
        float s = 0.f, s2 = 0.f;
        for (int c = 0; c < 256; c++){ s += z_s[c]; s2 += z_s[c]*z_s[c]; }
        float mean = s / 256.f, var = s2 / 256.f - mean*mean;
        stat[0] = mean; stat[1] = rsqrtf(var + 1e-6f);
    }
    __syncthreads();
    float h = g[t] * ((z - stat[0]) * stat[1]) + bta[t];
    bp[b*256 + t] = gelu_f(h);
}

// ---------------- broadcast pooled branch into catT cols 1024..1279 ----------------
__global__ void k_bcastT(const float* __restrict__ bp, unsigned short* __restrict__ catT){
    int b = blockIdx.y;
    int i = blockIdx.x*256 + threadIdx.x;
    int p = i >> 5, cj = (i & 31) * 8;
    s8v v8;
    #pragma unroll
    for (int k = 0; k < 8; k++) v8[k] = (short)f2bf(bp[b*256 + cj + k]);
    *(s8v*)(catT + ((long long)b*HW + p)*1280 + 1024 + cj) = v8;
}

// ---------------- attention pass 1 (split-j, dbuf LDS, global Q frags) ----------------
__global__ __launch_bounds__(256)
void k_attn_stats2(const unsigned short* __restrict__ QT,
                   const unsigned short* __restrict__ PT,
                   float* __restrict__ mpart, float* __restrict__ lpart){
    int b = blockIdx.z, jc = blockIdx.y, k0 = blockIdx.x * 64;
    const unsigned short* QTb = QT + (long long)b * HW * CO;
    const unsigned short* PTb = PT + (long long)b * HW * CO;
    __shared__ unsigned short Ps[2][64][132];
    int t = threadIdx.x;
    int w = t >> 6, lane = t & 63, m = lane & 15, q = lane >> 4;
    s8v a[4];
    #pragma unroll
    for (int ks = 0; ks < 4; ks++)
        a[ks] = *(const s8v*)(QTb + (long long)(k0 + w*16 + m) * CO + q*8 + ks*32);
    float rm[4], rl[4];
    #pragma unroll
    for (int r = 0; r < 4; r++){ rm[r] = -1e30f; rl[r] = 0.f; }
    const float scale = 0.015625f;           // 1/sqrt(4096)
    int jbase = jc * 1024;
    int sr = t >> 2, sch = t & 3;
    uint4 pf[4];
    {   const uint4* src = (const uint4*)(PTb + (long long)(jbase + sr) * CO + sch * 32);
        #pragma unroll
        for (int i = 0; i < 4; i++) pf[i] = src[i];
    }
    for (int jt = 0; jt < 16; jt++){
        int cur = jt & 1;
        {   uint4* dst = (uint4*)&Ps[cur][sr][sch * 32];
            #pragma unroll
            for (int i = 0; i < 4; i++) dst[i] = pf[i];
        }
        __syncthreads();
        if (jt < 15){
            const uint4* src = (const uint4*)(PTb + (long long)(jbase + (jt+1)*64 + sr) * CO + sch * 32);
            #pragma unroll
            for (int i = 0; i < 4; i++) pf[i] = src[i];
        }
        float sv[4][4];
        #pragma unroll
        for (int ct = 0; ct < 4; ct++){
            f4v acc = {0.f,0.f,0.f,0.f};
            #pragma unroll
            for (int ks = 0; ks < 4; ks++){
                s8v bv = *(const s8v*)&Ps[cur][ct*16 + m][q*8 + ks*32];
                acc = __builtin_amdgcn_mfma_f32_16x16x32_bf16(a[ks], bv, acc, 0, 0, 0);
            }
            #pragma unroll
            for (int r = 0; r < 4; r++) sv[ct][r] = acc[r] * scale;
        }
        #pragma unroll
        for (int r = 0; r < 4; r++){
            float mx = fmaxf(fmaxf(sv[0][r], sv[1][r]), fmaxf(sv[2][r], sv[3][r]));
            #pragma unroll
            for (int msk = 1; msk < 16; msk <<= 1) mx = fmaxf(mx, __shfl_xor(mx, msk));
            float nm = fmaxf(rm[r], mx);
            float se = __expf(sv[0][r]-nm) + __expf(sv[1][r]-nm)
                     + __expf(sv[2][r]-nm) + __expf(sv[3][r]-nm);
            #pragma unroll
            for (int msk = 1; msk < 16; msk <<= 1) se += __shfl_xor(se, msk);
            rl[r] = rl[r] * __expf(rm[r] - nm) + se;
            rm[r] = nm;
        }
    }
    if (m == 0){
        #pragma unroll
        for (int r = 0; r < 4; r++){
            int k = k0 + w*16 + q*4 + r;
            long long idx = (long long)jc * (NB*HW) + (long long)b*HW + k;
            mpart[idx] = rm[r];
            lpart[idx] = rl[r];
        }
    }
}

// ---------------- combine partial softmax stats ----------------
__global__ void k_attn_comb(const float* __restrict__ mpart, const float* __restrict__ lpart,
                            float* __restrict__ mrow, float* __restrict__ ilrow){
    int i = blockIdx.x*256 + threadIdx.x;
    float m0 = mpart[i], m1 = mpart[i+16384], m2 = mpart[i+32768], m3 = mpart[i+49152];
    float m = fmaxf(fmaxf(m0,m1), fmaxf(m2,m3));
    float l = lpart[i]*__expf(m0-m) + lpart[i+16384]*__expf(m1-m)
            + lpart[i+32768]*__expf(m2-m) + lpart[i+49152]*__expf(m3-m);
    mrow[i] = m;
    ilrow[i] = 1.f / l;
}

// ---------------- attention pass 2 (split-k, dbuf Q-tile, global P frags) ----------------
__global__ __launch_bounds__(256)
void k_attn_apply2(const unsigned short* __restrict__ QT,
                   const unsigned short* __restrict__ PT,
                   const unsigned short* __restrict__ Pb,
                   const float* __restrict__ mrow, const float* __restrict__ ilrow,
                   float* __restrict__ Lp){
    int b = blockIdx.z, kc = blockIdx.y, j0 = blockIdx.x * 64;
    const unsigned short* QTb = QT + (long long)b * HW * CO;
    const unsigned short* PTb = PT + (long long)b * HW * CO;
    const unsigned short* Pbb = Pb + (long long)b * CO * HW;
    const float* mb = mrow + (long long)b * HW;
    const float* lb = ilrow + (long long)b * HW;
    __shared__ unsigned short Qks[2][64][132];
    __shared__ unsigned short Et[64][68];
    int t = threadIdx.x;
    int w = t >> 6, lane = t & 63, m = lane & 15, q = lane >> 4;
    // bj frags (PT j-tile) direct from global
    s8v bj[4][4];
    #pragma unroll
    for (int ct = 0; ct < 4; ct++)
        #pragma unroll
        for (int ks = 0; ks < 4; ks++)
            bj[ct][ks] = *(const s8v*)(PTb + (long long)(j0 + ct*16 + m) * CO + q*8 + ks*32);
    f4v accL[2][4];
    #pragma unroll
    for (int mt = 0; mt < 2; mt++)
        #pragma unroll
        for (int ct = 0; ct < 4; ct++){ f4v z = {0.f,0.f,0.f,0.f}; accL[mt][ct] = z; }
    const float scale = 0.015625f;
    int kbase = kc * 1024;
    int sr = t >> 2, sch = t & 3;
    uint4 pf[4];
    {   const uint4* src = (const uint4*)(QTb + (long long)(kbase + sr) * CO + sch * 32);
        #pragma unroll
        for (int i = 0; i < 4; i++) pf[i] = src[i];
    }
    for (int kt = 0; kt < 16; kt++){
        int k0 = kbase + kt*64;
        int cur = kt & 1;
        {   uint4* dst = (uint4*)&Qks[cur][sr][sch * 32];
            #pragma unroll
            for (int i = 0; i < 4; i++) dst[i] = pf[i];
        }
        __syncthreads();
        if (kt < 15){
            const uint4* src = (const uint4*)(QTb + (long long)(k0 + 64 + sr) * CO + sch * 32);
            #pragma unroll
            for (int i = 0; i < 4; i++) pf[i] = src[i];
        }
        // P A-frags direct from global (L2-resident), overlap with S MFMAs below
        s8v aP[2][2];
        #pragma unroll
        for (int mt = 0; mt < 2; mt++)
            #pragma unroll
            for (int ks2 = 0; ks2 < 2; ks2++)
                aP[mt][ks2] = *(const s8v*)(Pbb + (long long)(w*32 + mt*16 + m) * HW + k0 + ks2*32 + q*8);
        float mk[4], il[4];
        #pragma unroll
        for (int r = 0; r < 4; r++){
            int kg = k0 + w*16 + q*4 + r;
            mk[r] = mb[kg]; il[r] = lb[kg];
        }
        s8v aS[4];
        #pragma unroll
        for (int ks = 0; ks < 4; ks++) aS[ks] = *(const s8v*)&Qks[cur][w*16 + m][q*8 + ks*32];
        #pragma unroll
        for (int ct = 0; ct < 4; ct++){
            f4v s = {0.f,0.f,0.f,0.f};
            #pragma unroll
            for (int ks = 0; ks < 4; ks++)
                s = __builtin_amdgcn_mfma_f32_16x16x32_bf16(aS[ks], bj[ct][ks], s, 0, 0, 0);
            s4v e4;
            #pragma unroll
            for (int r = 0; r < 4; r++)
                e4[r] = (short)f2bf(__expf(s[r]*scale - mk[r]) * il[r]);
            *(s4v*)&Et[ct*16 + m][w*16 + q*4] = e4;
        }
        __syncthreads();
        #pragma unroll
        for (int ct = 0; ct < 4; ct++){
            s8v bE0 = *(const s8v*)&Et[ct*16 + m][q*8];
            s8v bE1 = *(const s8v*)&Et[ct*16 + m][q*8 + 32];
            #pragma unroll
            for (int mt = 0; mt < 2; mt++){
                accL[mt][ct] = __builtin_amdgcn_mfma_f32_16x16x32_bf16(aP[mt][0], bE0, accL[mt][ct], 0, 0, 0);
                accL[mt][ct] = __builtin_amdgcn_mfma_f32_16x16x32_bf16(aP[mt][1], bE1, accL[mt][ct], 0, 0, 0);
            }
        }
    }
    float* Lpb = Lp + ((long long)(kc*NB + b) * CO) * HW;
    #pragma unroll
    for (int mt = 0; mt < 2; mt++)
        #pragma unroll
        for (int ct = 0; ct < 4; ct++)
            #pragma unroll
            for (int r = 0; r < 4; r++){
                int c = w*32 + mt*16 + q*4 + r;
                Lpb[(long long)c*HW + j0 + ct*16 + m] = accL[mt][ct][r];
            }
}

// ---------------- combine L partials + xa -> OT bf16 (transposed) ----------------
__global__ __launch_bounds__(256)
void k_attn_fin(const float* __restrict__ Lp, const float* __restrict__ xa,
                unsigned short* __restrict__ OT){
    int b = blockIdx.z, c0 = blockIdx.y*64, j0 = blockIdx.x*64;
    __shared__ unsigned short T[64][66];
    int t = threadIdx.x;
    int jl = t & 63, cs = t >> 6;
    const long long csz = (long long)NB*CO*HW;
    #pragma unroll
    for (int r = 0; r < 16; r++){
        int c = cs*16 + r;
        long long idx = ((long long)b*CO + c0 + c)*HW + j0 + jl;
        float v = xa[idx] + Lp[idx] + Lp[idx+csz] + Lp[idx+2*csz] + Lp[idx+3*csz];
        T[c][jl] = f2bf(v);
    }
    __syncthreads();
    int cl = t & 63, js = t >> 6;
    #pragma unroll
    for (int r = 0; r < 16; r++){
        int j = js*16 + r;
        OT[((long long)b*HW + j0 + j)*128 + c0 + cl] = T[cl][j];
    }
}

extern "C" void kernel_launch(void* const* d_in, const int* in_sizes, int n_in,
                              void* d_out, int out_size, void* d_ws, size_t ws_size,
                              hipStream_t stream) {
    const float* x       = (const float*)d_in[0];
    const float* conv1_w = (const float*)d_in[1];
    const float* conv1_b = (const float*)d_in[2];
    const float* conv2_w = (const float*)d_in[3];
    const float* conv2_b = (const float*)d_in[4];
    const float* cw_w1   = (const float*)d_in[5];
    const float* cw_b1   = (const float*)d_in[6];
    const float* cw_g    = (const float*)d_in[7];
    const float* cw_bt   = (const float*)d_in[8];
    const float* cw_w2   = (const float*)d_in[9];
    const float* cw_b2   = (const float*)d_in[10];
    const float* a0_w    = (const float*)d_in[11];
    const float* a0_g    = (const float*)d_in[12];
    const float* a0_b    = (const float*)d_in[13];
    const float* a1_w    = (const float*)d_in[14];
    const float* a1_g    = (const float*)d_in[15];
    const float* a1_b    = (const float*)d_in[16];
    const float* a2_w    = (const float*)d_in[17];
    const float* a2_g    = (const float*)d_in[18];
    const float* a2_b    = (const float*)d_in[19];
    const float* a3_w    = (const float*)d_in[20];
    const float* a3_g    = (const float*)d_in[21];
    const float* a3_b    = (const float*)d_in[22];
    const float* ap_w    = (const float*)d_in[23];
    const float* ap_g    = (const float*)d_in[24];
    const float* ap_b    = (const float*)d_in[25];
    const float* pj_w    = (const float*)d_in[26];
    const float* pj_g    = (const float*)d_in[27];
    const float* pj_b    = (const float*)d_in[28];
    float* out = (float*)d_out;

    // ---- workspace layout ----
    float* ws    = (float*)d_ws;
    float* avg   = ws;                  // 1024
    float* mx    = ws + 1024;           // 1024
    float* sv    = ws + 2048;           // 1024
    float* gp    = ws + 3072;           // 1024
    float* bp    = ws + 4096;           // 1024
    float* mrow  = ws + 5120;           // 16384
    float* ilrow = ws + 21504;          // 16384
    float* xa    = ws + 37888;          // 2,097,152
    float* mpart = xa + 2097152;        // 65536
    float* lpart = mpart + 65536;       // 65536
    unsigned short* sb = (unsigned short*)(ws + 4232192);
    unsigned short* xT    = sb;                    // 4,194,304
    unsigned short* xcT   = sb + 4194304;          // 4,194,304
    unsigned short* catT  = sb + 8388608;          // 20,971,520
    unsigned short* projT = sb + 29360128;         // 4,194,304
    unsigned short* P_bf  = sb + 33554432;         // 2,097,152
    unsigned short* PT_bf = sb + 35651584;         // 2,097,152
    unsigned short* QT_bf = sb + 37748736;         // 2,097,152
    unsigned short* OT_bf = sb + 39845888;         // 2,097,152
    unsigned short* w_c1  = sb + 41943040;         // 32768
    unsigned short* w_a0  = sb + 41975808;         // 65536
    unsigned short* w_pj  = sb + 42041344;         // 327680
    unsigned short* w_c2  = sb + 42369024;         // 32768
    unsigned short* w_d3  = sb + 42401792;         // 589824
    unsigned short* w_d6  = sb + 42991616;         // 589824
    unsigned short* w_d9  = sb + 43581440;         // 589824
    float* Lp = (float*)catT;           // alias: catT dead after proj (33.5MB in 42MB region)

    // ---- stats + channel weighting ----
    k_rowstats<<<dim3(NB*CI), 256, 0, stream>>>(x, avg, mx);
    k_cw<<<dim3(NB), 256, 0, stream>>>(avg, mx, cw_w1, cw_b1, cw_g, cw_bt, cw_w2, cw_b2, sv, gp);

    // ---- weight casts ----
    k_wcast<<<dim3(128),  256, 0, stream>>>(conv1_w, w_c1);
    k_wcast<<<dim3(256),  256, 0, stream>>>(a0_w,    w_a0);
    k_wcast<<<dim3(1280), 256, 0, stream>>>(pj_w,    w_pj);
    k_wcast<<<dim3(128),  256, 0, stream>>>(conv2_w, w_c2);
    k_w3<<<dim3(2304), 256, 0, stream>>>(a1_w, w_d3);
    k_w3<<<dim3(2304), 256, 0, stream>>>(a2_w, w_d6);
    k_w3<<<dim3(2304), 256, 0, stream>>>(a3_w, w_d9);

    // ---- x -> xT bf16 and xcT ----
    k_xT<<<dim3(64, 4, NB), 256, 0, stream>>>(x, sv, xT, xcT);

    // ---- x1 = conv1(x)+b -> P_bf/PT_bf ----
    k_conv1m<<<dim3(128, NB), 256, 0, stream>>>(w_c1, xT, conv1_b, PT_bf, P_bf, nullptr);

    // ---- ASPP branches (fused conv+LN+GELU -> catT bf16) ----
    k_branch1<<<dim3(128, NB), 512, 0, stream>>>(w_a0, 256, xcT, a0_g, a0_b, catT, 1280, 0);
    k_branch3<<<dim3(128, NB), 512, 0, stream>>>(w_d3, xcT, 3, a1_g, a1_b, catT, 256);
    k_branch3<<<dim3(128, NB), 512, 0, stream>>>(w_d6, xcT, 6, a2_g, a2_b, catT, 512);
    k_branch3<<<dim3(128, NB), 512, 0, stream>>>(w_d9, xcT, 9, a3_g, a3_b, catT, 768);
    k_pool<<<dim3(NB), 256, 0, stream>>>(gp, ap_w, ap_g, ap_b, bp);
    k_bcastT<<<dim3(512, NB), 256, 0, stream>>>(bp, catT);

    // ---- proj = GELU(LN(conv1x1(cat))) -> projT bf16 ----
    k_branch1<<<dim3(128, NB), 512, 0, stream>>>(w_pj, 1280, catT, pj_g, pj_b, projT, 256, 0);

    // ---- xa = conv1(proj)+b -> xa f32 + QT_bf ----
    k_conv1m<<<dim3(128, NB), 256, 0, stream>>>(w_c1, projT, conv1_b, QT_bf, nullptr, xa);

    // ---- attention ----
    k_attn_stats2<<<dim3(64, 4, NB), 256, 0, stream>>>(QT_bf, PT_bf, mpart, lpart);
    k_attn_comb<<<dim3(64), 256, 0, stream>>>(mpart, lpart, mrow, ilrow);
    k_attn_apply2<<<dim3(64, 4, NB), 256, 0, stream>>>(QT_bf, PT_bf, P_bf, mrow, ilrow, Lp);
    k_attn_fin<<<dim3(64, 2, NB), 256, 0, stream>>>(Lp, xa, OT_bf);

    // ---- out = conv2(O)+b ----
    k_gemm_out<<<dim3(128, NB), 256, 0, stream>>>(w_c2, OT_bf, conv2_b, out);

    (void)in_sizes; (void)n_in; (void)out_size; (void)ws_size;
}

// Round 7
// 600.869 us; speedup vs baseline: 1.0468x; 1.0468x over previous
//
#include <hip/hip_runtime.h>
#include <hip/hip_bf16.h>
#include <math.h>

// Problem constants (B=4, Cin=256, Cout=128, H=W=64)
#define NB 4
#define CI 256
#define CO 128
#define HW 4096

typedef __attribute__((ext_vector_type(8))) short s8v;   // 8 bf16 = 4 VGPRs (MFMA A/B frag)
typedef __attribute__((ext_vector_type(4))) short s4v;
typedef __attribute__((ext_vector_type(4))) float f4v;   // MFMA C/D frag

__device__ __forceinline__ unsigned short f2bf(float f){
    __hip_bfloat16 h = __float2bfloat16(f);   // RNE
    return *reinterpret_cast<unsigned short*>(&h);
}

// A&S 7.1.26 erf (max abs err 1.5e-7)
__device__ __forceinline__ float gelu_f(float x){
    float z  = x * 0.70710678118654752f;
    float az = fabsf(z);
    float tt = 1.f / (1.f + 0.3275911f * az);
    float poly = tt*(0.254829592f + tt*(-0.284496736f + tt*(1.421413741f +
                 tt*(-1.453152027f + tt*1.061405429f))));
    float erfv = 1.f - poly * __expf(-az*az);
    erfv = (z < 0.f) ? -erfv : erfv;
    return 0.5f * x * (1.f + erfv);
}

// ---------------- per-channel avg/max over HW ----------------
__global__ void k_rowstats(const float* __restrict__ x, float* __restrict__ avg, float* __restrict__ mx){
    int row = blockIdx.x;
    const float* p = x + (long long)row * HW;
    int t = threadIdx.x;
    float s = 0.f, m = -1e30f;
    for (int i = t; i < HW; i += 256){ float v = p[i]; s += v; m = fmaxf(m, v); }
    __shared__ float ss[256], sm[256];
    ss[t] = s; sm[t] = m; __syncthreads();
    for (int o = 128; o > 0; o >>= 1){
        if (t < o){ ss[t] += ss[t+o]; sm[t] = fmaxf(sm[t], sm[t+o]); }
        __syncthreads();
    }
    if (t == 0){ avg[row] = ss[0] / (float)HW; mx[row] = sm[0]; }
}

// ---------------- ChannelWeighting; also gp = avg*(1+s) ----------------
__global__ void k_cw(const float* __restrict__ avg, const float* __restrict__ mx,
                     const float* __restrict__ w1, const float* __restrict__ b1,
                     const float* __restrict__ lng, const float* __restrict__ lnb,
                     const float* __restrict__ w2, const float* __restrict__ b2,
                     float* __restrict__ sv, float* __restrict__ gp){
    int b = blockIdx.x, t = threadIdx.x;
    __shared__ float o_s[256];
    __shared__ float h_s[128];
    __shared__ float stat[2];
    float a = avg[b*256 + t];
    o_s[t] = fabsf(a - mx[b*256 + t]) * a;
    __syncthreads();
    if (t < 128){
        float h = b1[t];
        for (int i = 0; i < 256; i++) h += o_s[i] * w1[t*256 + i];
        h_s[t] = h;
    }
    __syncthreads();
    if (t == 0){
        float s = 0.f, s2 = 0.f;
        for (int j = 0; j < 128; j++){ s += h_s[j]; s2 += h_s[j]*h_s[j]; }
        float mean = s / 128.f;
        float var  = s2 / 128.f - mean*mean;
        stat[0] = mean; stat[1] = rsqrtf(var + 1e-5f);
    }
    __syncthreads();
    if (t < 128) h_s[t] = lng[t] * ((h_s[t] - stat[0]) * stat[1]) + lnb[t];
    __syncthreads();
    float z = b2[t];
    for (int j = 0; j < 128; j++) z += h_s[j] * w2[t*128 + j];
    float sig = 1.f / (1.f + __expf(-z));
    sv[b*256 + t] = sig;
    gp[b*256 + t] = a * (1.f + sig);
}

// ---------------- ALL weight casts in one launch ----------------
// ranges: c1[0,32768) a0[32768,98304) pj[98304,425984) c2[425984,458752)
//         d3/d6/d9: 589824 each, permuted [O][I][9] -> [tap][O][I]
__global__ void k_allcast(const float* __restrict__ c1, const float* __restrict__ a0,
                          const float* __restrict__ pj, const float* __restrict__ c2,
                          const float* __restrict__ d3, const float* __restrict__ d6,
                          const float* __restrict__ d9,
                          unsigned short* __restrict__ w_c1, unsigned short* __restrict__ w_a0,
                          unsigned short* __restrict__ w_pj, unsigned short* __restrict__ w_c2,
                          unsigned short* __restrict__ w_d3, unsigned short* __restrict__ w_d6,
                          unsigned short* __restrict__ w_d9){
    int i = blockIdx.x*256 + threadIdx.x;
    if (i < 458752){
        if (i < 32768)        w_c1[i]        = f2bf(c1[i]);
        else if (i < 98304)   w_a0[i-32768]  = f2bf(a0[i-32768]);
        else if (i < 425984)  w_pj[i-98304]  = f2bf(pj[i-98304]);
        else                  w_c2[i-425984] = f2bf(c2[i-425984]);
    } else {
        int j = i - 458752;
        int which = j / 589824;
        int l = j - which*589824;
        int tap = l >> 16, rem = l & 65535, o = rem >> 8, ci = rem & 255;
        const float* src = (which==0) ? d3 : ((which==1) ? d6 : d9);
        unsigned short* dst = (which==0) ? w_d3 : ((which==1) ? w_d6 : w_d9);
        dst[l] = f2bf(src[o*2304 + ci*9 + tap]);
    }
}

// ---------------- x -> xT bf16 [b][HW][256] and xcT = bf16(x*(1+s)) ----------------
__global__ void k_xT(const float* __restrict__ x, const float* __restrict__ sv,
                     unsigned short* __restrict__ xT, unsigned short* __restrict__ xcT){
    int b = blockIdx.z, c0 = blockIdx.y*64, h0 = blockIdx.x*64;
    __shared__ unsigned short T1[64][66], T2[64][66];
    int t = threadIdx.x;
    int hl = t & 63, cs = t >> 6;
    #pragma unroll
    for (int r = 0; r < 16; r++){
        int c = cs*16 + r;
        float v = x[((long long)b*256 + c0 + c)*HW + h0 + hl];
        float sc = 1.f + sv[b*256 + c0 + c];
        T1[c][hl] = f2bf(v);
        T2[c][hl] = f2bf(v*sc);
    }
    __syncthreads();
    int cl = t & 63, hs = t >> 6;
    #pragma unroll
    for (int r = 0; r < 16; r++){
        int h = hs*16 + r;
        long long o = ((long long)b*HW + h0 + h)*256 + c0 + cl;
        xT[o]  = T1[cl][h];
        xcT[o] = T2[cl][h];
    }
}

// ============ 8-wave epilogue, N=32: LN(256ch)+GELU -> transposed bf16 ============
__device__ __forceinline__ void ln_epi32(f4v acc[2][2],
        int b, int n0, int w, int lane, int m, int q, int t,
        const float* Gs, const float* Bts,
        float (*Psum)[32], float (*Psq)[32], float* Mn, float* Iv,
        unsigned short* __restrict__ outT, int outPitch, int colOff){
    float ls[2], ls2[2];
    #pragma unroll
    for (int ct = 0; ct < 2; ct++){
        float s = 0.f, s2 = 0.f;
        #pragma unroll
        for (int ms = 0; ms < 2; ms++)
            #pragma unroll
            for (int r = 0; r < 4; r++){ float v = acc[ms][ct][r]; s += v; s2 += v*v; }
        ls[ct] = s; ls2[ct] = s2;
    }
    #pragma unroll
    for (int ct = 0; ct < 2; ct++){
        ls[ct]  += __shfl_xor(ls[ct], 16);  ls[ct]  += __shfl_xor(ls[ct], 32);
        ls2[ct] += __shfl_xor(ls2[ct], 16); ls2[ct] += __shfl_xor(ls2[ct], 32);
    }
    if (lane < 16){
        #pragma unroll
        for (int ct = 0; ct < 2; ct++){ Psum[w][ct*16+lane] = ls[ct]; Psq[w][ct*16+lane] = ls2[ct]; }
    }
    __syncthreads();
    if (t < 32){
        float s = 0.f, s2 = 0.f;
        #pragma unroll
        for (int ww = 0; ww < 8; ww++){ s += Psum[ww][t]; s2 += Psq[ww][t]; }
        float mean = s * (1.f/256.f);
        Mn[t] = mean;
        Iv[t] = rsqrtf(s2*(1.f/256.f) - mean*mean + 1e-6f);
    }
    __syncthreads();
    #pragma unroll
    for (int ct = 0; ct < 2; ct++){
        int p = ct*16 + m;
        float mean = Mn[p], inv = Iv[p];
        long long rowb = ((long long)b*HW + n0 + p)*outPitch + colOff;
        #pragma unroll
        for (int ms = 0; ms < 2; ms++){
            s4v o4;
            #pragma unroll
            for (int r = 0; r < 4; r++){
                int c = w*32 + ms*16 + q*4 + r;
                float h = Gs[c]*((acc[ms][ct][r] - mean)*inv) + Bts[c];
                o4[r] = (short)f2bf(gelu_f(h));
            }
            *(s4v*)(outT + rowb + w*32 + ms*16 + q*4) = o4;
        }
    }
}

// ---------------- fused 1x1-conv (MFMA) + LN + GELU, 512 thr, N=32, Kstage=64 ----------------
__global__ __launch_bounds__(512)
void k_branch1(const unsigned short* __restrict__ A, int K,
               const unsigned short* __restrict__ BT,
               const float* __restrict__ g, const float* __restrict__ beta,
               unsigned short* __restrict__ outT, int outPitch, int colOff){
    int b = blockIdx.y, n0 = blockIdx.x*32;
    const unsigned short* BTb = BT + (long long)b*HW*K;
    __shared__ unsigned short As[256][72];
    __shared__ unsigned short Bs[32][72];
    __shared__ float Psum[8][32], Psq[8][32], Mn[32], Iv[32];
    __shared__ float Gs[256], Bts[256];
    int t = threadIdx.x, w = t>>6, lane = t&63, m = lane&15, q = lane>>4;
    if (t < 256){ Gs[t] = g[t]; Bts[t] = beta[t]; }
    f4v acc[2][2];
    #pragma unroll
    for (int ms = 0; ms < 2; ms++)
        #pragma unroll
        for (int ct = 0; ct < 2; ct++){ f4v z = {0.f,0.f,0.f,0.f}; acc[ms][ct] = z; }
    for (int k0 = 0; k0 < K; k0 += 64){
        __syncthreads();
        {   int r = t>>1, half = t&1;
            const uint4* src = (const uint4*)(A + (long long)r*K + k0 + half*32);
            uint4* dst = (uint4*)&As[r][half*32];
            dst[0]=src[0]; dst[1]=src[1]; dst[2]=src[2]; dst[3]=src[3];
        }
        {   int n = t>>4, ch = t&15;
            *(uint2*)&Bs[n][ch*4] = *(const uint2*)(BTb + (long long)(n0+n)*K + k0 + ch*4);
        }
        __syncthreads();
        #pragma unroll
        for (int ks = 0; ks < 2; ks++){
            s8v bfr[2];
            #pragma unroll
            for (int ct = 0; ct < 2; ct++) bfr[ct] = *(const s8v*)&Bs[ct*16+m][q*8+ks*32];
            #pragma unroll
            for (int ms = 0; ms < 2; ms++){
                s8v afr = *(const s8v*)&As[w*32 + ms*16 + m][q*8+ks*32];
                #pragma unroll
                for (int ct = 0; ct < 2; ct++)
                    acc[ms][ct] = __builtin_amdgcn_mfma_f32_16x16x32_bf16(afr, bfr[ct], acc[ms][ct], 0,0,0);
            }
        }
    }
    __syncthreads();
    ln_epi32(acc, b, n0, w, lane, m, q, t, Gs, Bts, Psum, Psq, Mn, Iv, outT, outPitch, colOff);
}

// ---------------- fused 3x3 dilated conv (MFMA) + LN + GELU, 512 thr, N=32, Kstage=64 ----------------
__global__ __launch_bounds__(512)
void k_branch3(const unsigned short* __restrict__ Wb,
               const unsigned short* __restrict__ BT, int d,
               const float* __restrict__ g, const float* __restrict__ beta,
               unsigned short* __restrict__ outT, int colOff){
    int b = blockIdx.y;
    int y = blockIdx.x >> 1, x0 = (blockIdx.x & 1)*32;
    int n0 = y*64 + x0;
    const unsigned short* BTb = BT + (long long)b*HW*256;
    __shared__ unsigned short As[256][72];
    __shared__ unsigned short Bs[32][72];
    __shared__ float Psum[8][32], Psq[8][32], Mn[32], Iv[32];
    __shared__ float Gs[256], Bts[256];
    int t = threadIdx.x, w = t>>6, lane = t&63, m = lane&15, q = lane>>4;
    if (t < 256){ Gs[t] = g[t]; Bts[t] = beta[t]; }
    f4v acc[2][2];
    #pragma unroll
    for (int ms = 0; ms < 2; ms++)
        #pragma unroll
        for (int ct = 0; ct < 2; ct++){ f4v z = {0.f,0.f,0.f,0.f}; acc[ms][ct] = z; }
    for (int tap = 0; tap < 9; tap++){
        int dy = tap/3 - 1, dx = tap%3 - 1;
        int ys = y + dy*d;
        bool yok = (unsigned)ys < 64u;
        const unsigned short* wtap = Wb + (long long)tap*65536;
        for (int kc = 0; kc < 4; kc++){
            int ci0 = kc*64;
            __syncthreads();
            {   int r = t>>1, half = t&1;
                const uint4* src = (const uint4*)(wtap + (long long)r*256 + ci0 + half*32);
                uint4* dst = (uint4*)&As[r][half*32];
                dst[0]=src[0]; dst[1]=src[1]; dst[2]=src[2]; dst[3]=src[3];
            }
            {   int n = t>>4, ch = t&15;
                int xs = x0 + n + dx*d;
                uint2 v = {0u,0u};
                if (yok && (unsigned)xs < 64u)
                    v = *(const uint2*)(BTb + (long long)(ys*64+xs)*256 + ci0 + ch*4);
                *(uint2*)&Bs[n][ch*4] = v;
            }
            __syncthreads();
            #pragma unroll
            for (int ks = 0; ks < 2; ks++){
                s8v bfr[2];
                #pragma unroll
                for (int ct = 0; ct < 2; ct++) bfr[ct] = *(const s8v*)&Bs[ct*16+m][q*8+ks*32];
                #pragma unroll
                for (int ms = 0; ms < 2; ms++){
                    s8v afr = *(const s8v*)&As[w*32 + ms*16 + m][q*8+ks*32];
                    #pragma unroll
                    for (int ct = 0; ct < 2; ct++)
                        acc[ms][ct] = __builtin_amdgcn_mfma_f32_16x16x32_bf16(afr, bfr[ct], acc[ms][ct], 0,0,0);
                }
            }
        }
    }
    __syncthreads();
    ln_epi32(acc, b, n0, w, lane, m, q, t, Gs, Bts, Psum, Psq, Mn, Iv, outT, 1280, colOff);
}

// ---------------- conv1 (M=128) MFMA, 256 thr, N=32, Kstage=64 ----------------
__global__ __launch_bounds__(256)
void k_conv1m(const unsigned short* __restrict__ A,      // [128][256] bf16
              const unsigned short* __restrict__ BT,     // [b][HW][256] bf16
              const float* __restrict__ bias,
              unsigned short* __restrict__ outT,         // [b][HW][128] bf16
              unsigned short* __restrict__ outC,         // [b][128][HW] bf16 or null
              float* __restrict__ outF){                 // [b][128][HW] f32 or null
    int b = blockIdx.y, n0 = blockIdx.x*32;
    const unsigned short* BTb = BT + (long long)b*HW*256;
    __shared__ unsigned short As[128][72];
    __shared__ unsigned short Bs[32][72];
    int t = threadIdx.x, w = t>>6, lane = t&63, m = lane&15, q = lane>>4;
    f4v acc[2][2];
    #pragma unroll
    for (int ms = 0; ms < 2; ms++)
        #pragma unroll
        for (int ct = 0; ct < 2; ct++){ f4v z = {0.f,0.f,0.f,0.f}; acc[ms][ct] = z; }
    for (int k0 = 0; k0 < 256; k0 += 64){
        __syncthreads();
        {   int r = t>>1, half = t&1;
            const uint4* src = (const uint4*)(A + (long long)r*256 + k0 + half*32);
            uint4* dst = (uint4*)&As[r][half*32];
            dst[0]=src[0]; dst[1]=src[1]; dst[2]=src[2]; dst[3]=src[3];
        }
        {   int n = t>>3, ch = t&7;
            *(uint4*)&Bs[n][ch*8] = *(const uint4*)(BTb + (long long)(n0+n)*256 + k0 + ch*8);
        }
        __syncthreads();
        #pragma unroll
        for (int ks = 0; ks < 2; ks++){
            s8v bfr[2];
            #pragma unroll
            for (int ct = 0; ct < 2; ct++) bfr[ct] = *(const s8v*)&Bs[ct*16+m][q*8+ks*32];
            #pragma unroll
            for (int ms = 0; ms < 2; ms++){
                s8v afr = *(const s8v*)&As[w*32 + ms*16 + m][q*8+ks*32];
                #pragma unroll
                for (int ct = 0; ct < 2; ct++)
                    acc[ms][ct] = __builtin_amdgcn_mfma_f32_16x16x32_bf16(afr, bfr[ct], acc[ms][ct], 0,0,0);
            }
        }
    }
    #pragma unroll
    for (int ct = 0; ct < 2; ct++){
        int p = n0 + ct*16 + m;
        #pragma unroll
        for (int ms = 0; ms < 2; ms++){
            s4v o4;
            float vals[4];
            #pragma unroll
            for (int r = 0; r < 4; r++){
                int c = w*32 + ms*16 + q*4 + r;
                vals[r] = acc[ms][ct][r] + bias[c];
                o4[r] = (short)f2bf(vals[r]);
            }
            *(s4v*)(outT + ((long long)b*HW + p)*128 + w*32 + ms*16 + q*4) = o4;
            if (outC){
                #pragma unroll
                for (int r = 0; r < 4; r++){
                    int c = w*32 + ms*16 + q*4 + r;
                    outC[((long long)b*128 + c)*HW + p] = (unsigned short)o4[r];
                }
            }
            if (outF){
                #pragma unroll
                for (int r = 0; r < 4; r++){
                    int c = w*32 + ms*16 + q*4 + r;
                    outF[((long long)b*128 + c)*HW + p] = vals[r];
                }
            }
        }
    }
}

// ---------------- pooled branch fused with broadcast into catT cols 1024..1279 ----------------
__global__ __launch_bounds__(256)
void k_poolbcast(const float* __restrict__ gp, const float* __restrict__ w,
                 const float* __restrict__ g, const float* __restrict__ bta,
                 unsigned short* __restrict__ catT){
    int b = blockIdx.y, p0 = blockIdx.x*128;
    int t = threadIdx.x;
    __shared__ float z_s[256];
    __shared__ unsigned short bp_s[256];
    __shared__ float stat[2];
    float z = 0.f;
    for (int c = 0; c < 256; c++) z += gp[b*256 + c] * w[t*256 + c];
    z_s[t] = z;
    __syncthreads();
    if (t == 0){
        float s = 0.f, s2 = 0.f;
        for (int c = 0; c < 256; c++){ s += z_s[c]; s2 += z_s[c]*z_s[c]; }
        float mean = s / 256.f, var = s2 / 256.f - mean*mean;
        stat[0] = mean; stat[1] = rsqrtf(var + 1e-6f);
    }
    __syncthreads();
    float h = g[t] * ((z - stat[0]) * stat[1]) + bta[t];
    bp_s[t] = f2bf(gelu_f(h));
    __syncthreads();
    for (int it = 0; it < 16; it++){
        int i = it*256 + t;
        int pl = i >> 5, cj = (i & 31) * 8;
        s8v v8;
        #pragma unroll
        for (int k2 = 0; k2 < 8; k2++) v8[k2] = (short)bp_s[cj + k2];
        *(s8v*)(catT + ((long long)b*HW + p0 + pl)*1280 + 1024 + cj) = v8;
    }
}

// ---------------- attention pass 1 (split-j, dbuf LDS Ps, global Q frags) ----------------
__global__ __launch_bounds__(256)
void k_attn_stats2(const unsigned short* __restrict__ QT,
                   const unsigned short* __restrict__ PT,
                   float* __restrict__ mpart, float* __restrict__ lpart){
    int b = blockIdx.z, jc = blockIdx.y, k0 = blockIdx.x * 64;
    const unsigned short* QTb = QT + (long long)b * HW * CO;
    const unsigned short* PTb = PT + (long long)b * HW * CO;
    __shared__ unsigned short Ps[2][64][132];
    int t = threadIdx.x;
    int w = t >> 6, lane = t & 63, m = lane & 15, q = lane >> 4;
    s8v a[4];
    #pragma unroll
    for (int ks = 0; ks < 4; ks++)
        a[ks] = *(const s8v*)(QTb + (long long)(k0 + w*16 + m) * CO + q*8 + ks*32);
    float rm[4], rl[4];
    #pragma unroll
    for (int r = 0; r < 4; r++){ rm[r] = -1e30f; rl[r] = 0.f; }
    const float scale = 0.015625f;           // 1/sqrt(4096)
    int jbase = jc * 1024;
    int sr = t >> 2, sch = t & 3;
    uint4 pf[4];
    {   const uint4* src = (const uint4*)(PTb + (long long)(jbase + sr) * CO + sch * 32);
        #pragma unroll
        for (int i = 0; i < 4; i++) pf[i] = src[i];
    }
    for (int jt = 0; jt < 16; jt++){
        int cur = jt & 1;
        {   uint4* dst = (uint4*)&Ps[cur][sr][sch * 32];
            #pragma unroll
            for (int i = 0; i < 4; i++) dst[i] = pf[i];
        }
        __syncthreads();
        if (jt < 15){
            const uint4* src = (const uint4*)(PTb + (long long)(jbase + (jt+1)*64 + sr) * CO + sch * 32);
            #pragma unroll
            for (int i = 0; i < 4; i++) pf[i] = src[i];
        }
        float sv[4][4];
        #pragma unroll
        for (int ct = 0; ct < 4; ct++){
            f4v acc = {0.f,0.f,0.f,0.f};
            #pragma unroll
            for (int ks = 0; ks < 4; ks++){
                s8v bv = *(const s8v*)&Ps[cur][ct*16 + m][q*8 + ks*32];
                acc = __builtin_amdgcn_mfma_f32_16x16x32_bf16(a[ks], bv, acc, 0, 0, 0);
            }
            #pragma unroll
            for (int r = 0; r < 4; r++) sv[ct][r] = acc[r] * scale;
        }
        #pragma unroll
        for (int r = 0; r < 4; r++){
            float mx = fmaxf(fmaxf(sv[0][r], sv[1][r]), fmaxf(sv[2][r], sv[3][r]));
            #pragma unroll
            for (int msk = 1; msk < 16; msk <<= 1) mx = fmaxf(mx, __shfl_xor(mx, msk));
            float nm = fmaxf(rm[r], mx);
            float se = __expf(sv[0][r]-nm) + __expf(sv[1][r]-nm)
                     + __expf(sv[2][r]-nm) + __expf(sv[3][r]-nm);
            #pragma unroll
            for (int msk = 1; msk < 16; msk <<= 1) se += __shfl_xor(se, msk);
            rl[r] = rl[r] * __expf(rm[r] - nm) + se;
            rm[r] = nm;
        }
    }
    if (m == 0){
        #pragma unroll
        for (int r = 0; r < 4; r++){
            int k = k0 + w*16 + q*4 + r;
            long long idx = (long long)jc * (NB*HW) + (long long)b*HW + k;
            mpart[idx] = rm[r];
            lpart[idx] = rl[r];
        }
    }
}

// ---------------- attention pass 2 (split-k, LDS-staged, fused stat combine) ----------------
__global__ __launch_bounds__(256)
void k_attn_apply3(const unsigned short* __restrict__ QT,
                   const unsigned short* __restrict__ PT,
                   const unsigned short* __restrict__ Pb,
                   const float* __restrict__ mpart, const float* __restrict__ lpart,
                   float* __restrict__ Lp){
    int b = blockIdx.z, kc = blockIdx.y, j0 = blockIdx.x * 64;
    const unsigned short* QTb = QT + (long long)b * HW * CO;
    const unsigned short* PTb = PT + (long long)b * HW * CO;
    const unsigned short* Pbb = Pb + (long long)b * CO * HW;
    __shared__ unsigned short Qks[64][132];
    __shared__ unsigned short Pcs[128][68];
    __shared__ unsigned short Et[64][68];
    __shared__ float Ml[1024], Il[1024];
    int t = threadIdx.x;
    int w = t >> 6, lane = t & 63, m = lane & 15, q = lane >> 4;
    int kbase = kc * 1024;
    // fused combine: (m, 1/l) for this block's k-range
    {
        #pragma unroll
        for (int r = 0; r < 4; r++){
            int kl = t*4 + r;
            long long gi = (long long)b*HW + kbase + kl;
            float m0 = mpart[gi], m1 = mpart[gi+16384], m2 = mpart[gi+32768], m3 = mpart[gi+49152];
            float mm = fmaxf(fmaxf(m0,m1), fmaxf(m2,m3));
            float l = lpart[gi]*__expf(m0-mm) + lpart[gi+16384]*__expf(m1-mm)
                    + lpart[gi+32768]*__expf(m2-mm) + lpart[gi+49152]*__expf(m3-mm);
            Ml[kl] = mm;
            Il[kl] = 1.f / l;
        }
    }
    // bj frags (PT j-tile), one-time global load
    s8v bj[4][4];
    #pragma unroll
    for (int ct = 0; ct < 4; ct++)
        #pragma unroll
        for (int ks = 0; ks < 4; ks++)
            bj[ct][ks] = *(const s8v*)(PTb + (long long)(j0 + ct*16 + m) * CO + q*8 + ks*32);
    f4v accL[2][4];
    #pragma unroll
    for (int mt = 0; mt < 2; mt++)
        #pragma unroll
        for (int ct = 0; ct < 4; ct++){ f4v z = {0.f,0.f,0.f,0.f}; accL[mt][ct] = z; }
    const float scale = 0.015625f;
    for (int kt = 0; kt < 16; kt++){
        int k0 = kbase + kt*64;
        __syncthreads();
        {   int r = t >> 2, ch = t & 3;
            const uint4* src = (const uint4*)(QTb + (long long)(k0 + r) * CO + ch * 32);
            uint4* dst = (uint4*)&Qks[r][ch * 32];
            #pragma unroll
            for (int i = 0; i < 4; i++) dst[i] = src[i];
        }
        {   int c = t >> 1, hf = t & 1;
            const uint4* src = (const uint4*)(Pbb + (long long)c * HW + k0 + hf * 32);
            uint4* dst = (uint4*)&Pcs[c][hf * 32];
            #pragma unroll
            for (int i = 0; i < 4; i++) dst[i] = src[i];
        }
        __syncthreads();
        s8v aS[4];
        #pragma unroll
        for (int ks = 0; ks < 4; ks++) aS[ks] = *(const s8v*)&Qks[w*16 + m][q*8 + ks*32];
        float mk[4], il[4];
        #pragma unroll
        for (int r = 0; r < 4; r++){
            int kl = kt*64 + w*16 + q*4 + r;
            mk[r] = Ml[kl]; il[r] = Il[kl];
        }
        #pragma unroll
        for (int ct = 0; ct < 4; ct++){
            f4v s = {0.f,0.f,0.f,0.f};
            #pragma unroll
            for (int ks = 0; ks < 4; ks++)
                s = __builtin_amdgcn_mfma_f32_16x16x32_bf16(aS[ks], bj[ct][ks], s, 0, 0, 0);
            s4v e4;
            #pragma unroll
            for (int r = 0; r < 4; r++)
                e4[r] = (short)f2bf(__expf(s[r]*scale - mk[r]) * il[r]);
            *(s4v*)&Et[ct*16 + m][w*16 + q*4] = e4;
        }
        __syncthreads();
        s8v aP[2][2];
        #pragma unroll
        for (int mt = 0; mt < 2; mt++)
            #pragma unroll
            for (int ks2 = 0; ks2 < 2; ks2++)
                aP[mt][ks2] = *(const s8v*)&Pcs[w*32 + mt*16 + m][q*8 + ks2*32];
        #pragma unroll
        for (int ct = 0; ct < 4; ct++){
            s8v bE0 = *(const s8v*)&Et[ct*16 + m][q*8];
            s8v bE1 = *(const s8v*)&Et[ct*16 + m][q*8 + 32];
            #pragma unroll
            for (int mt = 0; mt < 2; mt++){
                accL[mt][ct] = __builtin_amdgcn_mfma_f32_16x16x32_bf16(aP[mt][0], bE0, accL[mt][ct], 0, 0, 0);
                accL[mt][ct] = __builtin_amdgcn_mfma_f32_16x16x32_bf16(aP[mt][1], bE1, accL[mt][ct], 0, 0, 0);
            }
        }
    }
    float* Lpb = Lp + ((long long)(kc*NB + b) * CO) * HW;
    #pragma unroll
    for (int mt = 0; mt < 2; mt++)
        #pragma unroll
        for (int ct = 0; ct < 4; ct++)
            #pragma unroll
            for (int r = 0; r < 4; r++){
                int c = w*32 + mt*16 + q*4 + r;
                Lpb[(long long)c*HW + j0 + ct*16 + m] = accL[mt][ct][r];
            }
}

// ---------------- fused: O = xa + sum(Lp) -> bf16 B-tile -> conv2 -> out f32 ----------------
__global__ __launch_bounds__(256)
void k_outfused(const unsigned short* __restrict__ A,    // w_c2 [256][128] bf16
                const float* __restrict__ Lp, const float* __restrict__ xa,
                const float* __restrict__ bias, float* __restrict__ out){
    int b = blockIdx.y, j0 = blockIdx.x*32;
    __shared__ unsigned short Bs[32][136];
    __shared__ __align__(16) char pool[256*68*2];   // phase1: Bsf[128][33] f32; phase2: As[256][68] bf16
    int t = threadIdx.x;
    // phase 1: O tile f32 = xa + 4 partials (coalesced c-rows)
    {
        float* Bsf = (float*)pool;
        int c = t>>1, jh = t&1;
        long long base = ((long long)b*CO + c)*HW + j0 + jh*16;
        const long long csz = (long long)NB*CO*HW;
        float v[16];
        #pragma unroll
        for (int r = 0; r < 16; r++) v[r] = xa[base + r];
        #pragma unroll
        for (int pidx = 0; pidx < 4; pidx++){
            const float* src = Lp + pidx*csz + base;
            #pragma unroll
            for (int r = 0; r < 16; r++) v[r] += src[r];
        }
        #pragma unroll
        for (int r = 0; r < 16; r++) Bsf[c*33 + jh*16 + r] = v[r];
    }
    __syncthreads();
    // transpose to bf16 B-tile [j][c]
    {
        const float* Bsf = (const float*)pool;
        int j = t>>3, cs = t&7;
        #pragma unroll
        for (int r = 0; r < 16; r++){
            int c = cs*16 + r;
            Bs[j][c] = f2bf(Bsf[c*33 + j]);
        }
    }
    __syncthreads();
    // phase 2: GEMM M=256 x N=32 x K=128
    unsigned short (*As)[68] = (unsigned short(*)[68])pool;
    int w = t>>6, lane = t&63, m = lane&15, q = lane>>4;
    f4v acc[4][2];
    #pragma unroll
    for (int ms = 0; ms < 4; ms++)
        #pragma unroll
        for (int ct = 0; ct < 2; ct++){ f4v z = {0.f,0.f,0.f,0.f}; acc[ms][ct] = z; }
    for (int k0 = 0; k0 < 128; k0 += 64){
        __syncthreads();
        {   const uint4* src = (const uint4*)(A + (long long)t*128 + k0);
            uint4* dst = (uint4*)&As[t][0];
            #pragma unroll
            for (int i = 0; i < 8; i++) dst[i] = src[i];
        }
        __syncthreads();
        #pragma unroll
        for (int ks = 0; ks < 2; ks++){
            s8v bfr[2];
            #pragma unroll
            for (int ct = 0; ct < 2; ct++) bfr[ct] = *(const s8v*)&Bs[ct*16+m][k0 + ks*32 + q*8];
            #pragma unroll
            for (int ms = 0; ms < 4; ms++){
                s8v afr = *(const s8v*)&As[w*64 + ms*16 + m][q*8 + ks*32];
                #pragma unroll
                for (int ct = 0; ct < 2; ct++)
                    acc[ms][ct] = __builtin_amdgcn_mfma_f32_16x16x32_bf16(afr, bfr[ct], acc[ms][ct], 0,0,0);
            }
        }
    }
    #pragma unroll
    for (int ct = 0; ct < 2; ct++){
        int p = j0 + ct*16 + m;
        #pragma unroll
        for (int ms = 0; ms < 4; ms++)
            #pragma unroll
            for (int r = 0; r < 4; r++){
                int c = w*64 + ms*16 + q*4 + r;
                out[((long long)b*256 + c)*HW + p] = acc[ms][ct][r] + bias[c];
            }
    }
}

extern "C" void kernel_launch(void* const* d_in, const int* in_sizes, int n_in,
                              void* d_out, int out_size, void* d_ws, size_t ws_size,
                              hipStream_t stream) {
    const float* x       = (const float*)d_in[0];
    const float* conv1_w = (const float*)d_in[1];
    const float* conv1_b = (const float*)d_in[2];
    const float* conv2_w = (const float*)d_in[3];
    const float* conv2_b = (const float*)d_in[4];
    const float* cw_w1   = (const float*)d_in[5];
    const float* cw_b1   = (const float*)d_in[6];
    const float* cw_g    = (const float*)d_in[7];
    const float* cw_bt   = (const float*)d_in[8];
    const float* cw_w2   = (const float*)d_in[9];
    const float* cw_b2   = (const float*)d_in[10];
    const float* a0_w    = (const float*)d_in[11];
    const float* a0_g    = (const float*)d_in[12];
    const float* a0_b    = (const float*)d_in[13];
    const float* a1_w    = (const float*)d_in[14];
    const float* a1_g    = (const float*)d_in[15];
    const float* a1_b    = (const float*)d_in[16];
    const float* a2_w    = (const float*)d_in[17];
    const float* a2_g    = (const float*)d_in[18];
    const float* a2_b    = (const float*)d_in[19];
    const float* a3_w    = (const float*)d_in[20];
    const float* a3_g    = (const float*)d_in[21];
    const float* a3_b    = (const float*)d_in[22];
    const float* ap_w    = (const float*)d_in[23];
    const float* ap_g    = (const float*)d_in[24];
    const float* ap_b    = (const float*)d_in[25];
    const float* pj_w    = (const float*)d_in[26];
    const float* pj_g    = (const float*)d_in[27];
    const float* pj_b    = (const float*)d_in[28];
    float* out = (float*)d_out;

    // ---- workspace layout ----
    float* ws    = (float*)d_ws;
    float* avg   = ws;                  // 1024
    float* mx    = ws + 1024;           // 1024
    float* sv    = ws + 2048;           // 1024
    float* gp    = ws + 3072;           // 1024
    float* bp    = ws + 4096;           // 1024 (unused)
    float* xa    = ws + 37888;          // 2,097,152
    float* mpart = xa + 2097152;        // 65536
    float* lpart = mpart + 65536;       // 65536
    unsigned short* sb = (unsigned short*)(ws + 4232192);
    unsigned short* xT    = sb;                    // 4,194,304
    unsigned short* xcT   = sb + 4194304;          // 4,194,304
    unsigned short* catT  = sb + 8388608;          // 20,971,520
    unsigned short* projT = sb + 29360128;         // 4,194,304
    unsigned short* P_bf  = sb + 33554432;         // 2,097,152
    unsigned short* PT_bf = sb + 35651584;         // 2,097,152
    unsigned short* QT_bf = sb + 37748736;         // 2,097,152
    unsigned short* w_c1  = sb + 41943040;         // 32768
    unsigned short* w_a0  = sb + 41975808;         // 65536
    unsigned short* w_pj  = sb + 42041344;         // 327680
    unsigned short* w_c2  = sb + 42369024;         // 32768
    unsigned short* w_d3  = sb + 42401792;         // 589824
    unsigned short* w_d6  = sb + 42991616;         // 589824
    unsigned short* w_d9  = sb + 43581440;         // 589824
    float* Lp = (float*)catT;           // alias: catT dead after proj (33.5MB in 42MB region)
    (void)bp;

    // ---- stats + channel weighting ----
    k_rowstats<<<dim3(NB*CI), 256, 0, stream>>>(x, avg, mx);
    k_cw<<<dim3(NB), 256, 0, stream>>>(avg, mx, cw_w1, cw_b1, cw_g, cw_bt, cw_w2, cw_b2, sv, gp);

    // ---- all weight casts (one launch) ----
    k_allcast<<<dim3(8704), 256, 0, stream>>>(conv1_w, a0_w, pj_w, conv2_w, a1_w, a2_w, a3_w,
                                              w_c1, w_a0, w_pj, w_c2, w_d3, w_d6, w_d9);

    // ---- x -> xT bf16 and xcT ----
    k_xT<<<dim3(64, 4, NB), 256, 0, stream>>>(x, sv, xT, xcT);

    // ---- x1 = conv1(x)+b -> P_bf/PT_bf ----
    k_conv1m<<<dim3(128, NB), 256, 0, stream>>>(w_c1, xT, conv1_b, PT_bf, P_bf, nullptr);

    // ---- ASPP branches (fused conv+LN+GELU -> catT bf16) ----
    k_branch1<<<dim3(128, NB), 512, 0, stream>>>(w_a0, 256, xcT, a0_g, a0_b, catT, 1280, 0);
    k_branch3<<<dim3(128, NB), 512, 0, stream>>>(w_d3, xcT, 3, a1_g, a1_b, catT, 256);
    k_branch3<<<dim3(128, NB), 512, 0, stream>>>(w_d6, xcT, 6, a2_g, a2_b, catT, 512);
    k_branch3<<<dim3(128, NB), 512, 0, stream>>>(w_d9, xcT, 9, a3_g, a3_b, catT, 768);
    k_poolbcast<<<dim3(32, NB), 256, 0, stream>>>(gp, ap_w, ap_g, ap_b, catT);

    // ---- proj = GELU(LN(conv1x1(cat))) -> projT bf16 ----
    k_branch1<<<dim3(128, NB), 512, 0, stream>>>(w_pj, 1280, catT, pj_g, pj_b, projT, 256, 0);

    // ---- xa = conv1(proj)+b -> xa f32 + QT_bf ----
    k_conv1m<<<dim3(128, NB), 256, 0, stream>>>(w_c1, projT, conv1_b, QT_bf, nullptr, xa);

    // ---- attention ----
    k_attn_stats2<<<dim3(64, 4, NB), 256, 0, stream>>>(QT_bf, PT_bf, mpart, lpart);
    k_attn_apply3<<<dim3(64, 4, NB), 256, 0, stream>>>(QT_bf, PT_bf, P_bf, mpart, lpart, Lp);

    // ---- out = conv2(xa + sum Lp) + b (fused) ----
    k_outfused<<<dim3(128, NB), 256, 0, stream>>>(w_c2, Lp, xa, conv2_b, out);

    (void)in_sizes; (void)n_in; (void)out_size; (void)ws_size;
}

// Round 8
// 571.943 us; speedup vs baseline: 1.0998x; 1.0506x over previous
//
#include <hip/hip_runtime.h>
#include <hip/hip_bf16.h>
#include <math.h>

// Problem constants (B=4, Cin=256, Cout=128, H=W=64)
#define NB 4
#define CI 256
#define CO 128
#define HW 4096

typedef __attribute__((ext_vector_type(8))) short s8v;   // 8 bf16 = 4 VGPRs (MFMA A/B frag)
typedef __attribute__((ext_vector_type(4))) short s4v;
typedef __attribute__((ext_vector_type(4))) float f4v;   // MFMA C/D frag

__device__ __forceinline__ unsigned short f2bf(float f){
    __hip_bfloat16 h = __float2bfloat16(f);   // RNE
    return *reinterpret_cast<unsigned short*>(&h);
}

// A&S 7.1.26 erf (max abs err 1.5e-7)
__device__ __forceinline__ float gelu_f(float x){
    float z  = x * 0.70710678118654752f;
    float az = fabsf(z);
    float tt = 1.f / (1.f + 0.3275911f * az);
    float poly = tt*(0.254829592f + tt*(-0.284496736f + tt*(1.421413741f +
                 tt*(-1.453152027f + tt*1.061405429f))));
    float erfv = 1.f - poly * __expf(-az*az);
    erfv = (z < 0.f) ? -erfv : erfv;
    return 0.5f * x * (1.f + erfv);
}

// ---------------- per-channel avg/max over HW ----------------
__global__ void k_rowstats(const float* __restrict__ x, float* __restrict__ avg, float* __restrict__ mx){
    int row = blockIdx.x;
    const float* p = x + (long long)row * HW;
    int t = threadIdx.x;
    float s = 0.f, m = -1e30f;
    for (int i = t; i < HW; i += 256){ float v = p[i]; s += v; m = fmaxf(m, v); }
    __shared__ float ss[256], sm[256];
    ss[t] = s; sm[t] = m; __syncthreads();
    for (int o = 128; o > 0; o >>= 1){
        if (t < o){ ss[t] += ss[t+o]; sm[t] = fmaxf(sm[t], sm[t+o]); }
        __syncthreads();
    }
    if (t == 0){ avg[row] = ss[0] / (float)HW; mx[row] = sm[0]; }
}

// ---------------- ChannelWeighting; also gp = avg*(1+s) ----------------
__global__ void k_cw(const float* __restrict__ avg, const float* __restrict__ mx,
                     const float* __restrict__ w1, const float* __restrict__ b1,
                     const float* __restrict__ lng, const float* __restrict__ lnb,
                     const float* __restrict__ w2, const float* __restrict__ b2,
                     float* __restrict__ sv, float* __restrict__ gp){
    int b = blockIdx.x, t = threadIdx.x;
    __shared__ float o_s[256];
    __shared__ float h_s[128];
    __shared__ float stat[2];
    float a = avg[b*256 + t];
    o_s[t] = fabsf(a - mx[b*256 + t]) * a;
    __syncthreads();
    if (t < 128){
        float h = b1[t];
        for (int i = 0; i < 256; i++) h += o_s[i] * w1[t*256 + i];
        h_s[t] = h;
    }
    __syncthreads();
    if (t == 0){
        float s = 0.f, s2 = 0.f;
        for (int j = 0; j < 128; j++){ s += h_s[j]; s2 += h_s[j]*h_s[j]; }
        float mean = s / 128.f;
        float var  = s2 / 128.f - mean*mean;
        stat[0] = mean; stat[1] = rsqrtf(var + 1e-5f);
    }
    __syncthreads();
    if (t < 128) h_s[t] = lng[t] * ((h_s[t] - stat[0]) * stat[1]) + lnb[t];
    __syncthreads();
    float z = b2[t];
    for (int j = 0; j < 128; j++) z += h_s[j] * w2[t*128 + j];
    float sig = 1.f / (1.f + __expf(-z));
    sv[b*256 + t] = sig;
    gp[b*256 + t] = a * (1.f + sig);
}

// ---------------- ALL weight casts in one launch ----------------
__global__ void k_allcast(const float* __restrict__ c1, const float* __restrict__ a0,
                          const float* __restrict__ pj, const float* __restrict__ c2,
                          const float* __restrict__ d3, const float* __restrict__ d6,
                          const float* __restrict__ d9,
                          unsigned short* __restrict__ w_c1, unsigned short* __restrict__ w_a0,
                          unsigned short* __restrict__ w_pj, unsigned short* __restrict__ w_c2,
                          unsigned short* __restrict__ w_d3, unsigned short* __restrict__ w_d6,
                          unsigned short* __restrict__ w_d9){
    int i = blockIdx.x*256 + threadIdx.x;
    if (i < 458752){
        if (i < 32768)        w_c1[i]        = f2bf(c1[i]);
        else if (i < 98304)   w_a0[i-32768]  = f2bf(a0[i-32768]);
        else if (i < 425984)  w_pj[i-98304]  = f2bf(pj[i-98304]);
        else                  w_c2[i-425984] = f2bf(c2[i-425984]);
    } else {
        int j = i - 458752;
        int which = j / 589824;
        int l = j - which*589824;
        int tap = l >> 16, rem = l & 65535, o = rem >> 8, ci = rem & 255;
        const float* src = (which==0) ? d3 : ((which==1) ? d6 : d9);
        unsigned short* dst = (which==0) ? w_d3 : ((which==1) ? w_d6 : w_d9);
        dst[l] = f2bf(src[o*2304 + ci*9 + tap]);
    }
}

// ---------------- x -> xT bf16 [b][HW][256] and xcT = bf16(x*(1+s)) ----------------
__global__ void k_xT(const float* __restrict__ x, const float* __restrict__ sv,
                     unsigned short* __restrict__ xT, unsigned short* __restrict__ xcT){
    int b = blockIdx.z, c0 = blockIdx.y*64, h0 = blockIdx.x*64;
    __shared__ unsigned short T1[64][66], T2[64][66];
    int t = threadIdx.x;
    int hl = t & 63, cs = t >> 6;
    #pragma unroll
    for (int r = 0; r < 16; r++){
        int c = cs*16 + r;
        float v = x[((long long)b*256 + c0 + c)*HW + h0 + hl];
        float sc = 1.f + sv[b*256 + c0 + c];
        T1[c][hl] = f2bf(v);
        T2[c][hl] = f2bf(v*sc);
    }
    __syncthreads();
    int cl = t & 63, hs = t >> 6;
    #pragma unroll
    for (int r = 0; r < 16; r++){
        int h = hs*16 + r;
        long long o = ((long long)b*HW + h0 + h)*256 + c0 + cl;
        xT[o]  = T1[cl][h];
        xcT[o] = T2[cl][h];
    }
}

// ============ 8-wave epilogue, N=32: LN(256ch)+GELU -> transposed bf16 ============
__device__ __forceinline__ void ln_epi32(f4v acc[2][2],
        int b, int n0, int w, int lane, int m, int q, int t,
        const float* Gs, const float* Bts,
        float (*Psum)[32], float (*Psq)[32], float* Mn, float* Iv,
        unsigned short* __restrict__ outT, int outPitch, int colOff){
    float ls[2], ls2[2];
    #pragma unroll
    for (int ct = 0; ct < 2; ct++){
        float s = 0.f, s2 = 0.f;
        #pragma unroll
        for (int ms = 0; ms < 2; ms++)
            #pragma unroll
            for (int r = 0; r < 4; r++){ float v = acc[ms][ct][r]; s += v; s2 += v*v; }
        ls[ct] = s; ls2[ct] = s2;
    }
    #pragma unroll
    for (int ct = 0; ct < 2; ct++){
        ls[ct]  += __shfl_xor(ls[ct], 16);  ls[ct]  += __shfl_xor(ls[ct], 32);
        ls2[ct] += __shfl_xor(ls2[ct], 16); ls2[ct] += __shfl_xor(ls2[ct], 32);
    }
    if (lane < 16){
        #pragma unroll
        for (int ct = 0; ct < 2; ct++){ Psum[w][ct*16+lane] = ls[ct]; Psq[w][ct*16+lane] = ls2[ct]; }
    }
    __syncthreads();
    if (t < 32){
        float s = 0.f, s2 = 0.f;
        #pragma unroll
        for (int ww = 0; ww < 8; ww++){ s += Psum[ww][t]; s2 += Psq[ww][t]; }
        float mean = s * (1.f/256.f);
        Mn[t] = mean;
        Iv[t] = rsqrtf(s2*(1.f/256.f) - mean*mean + 1e-6f);
    }
    __syncthreads();
    #pragma unroll
    for (int ct = 0; ct < 2; ct++){
        int p = ct*16 + m;
        float mean = Mn[p], inv = Iv[p];
        long long rowb = ((long long)b*HW + n0 + p)*outPitch + colOff;
        #pragma unroll
        for (int ms = 0; ms < 2; ms++){
            s4v o4;
            #pragma unroll
            for (int r = 0; r < 4; r++){
                int c = w*32 + ms*16 + q*4 + r;
                float h = Gs[c]*((acc[ms][ct][r] - mean)*inv) + Bts[c];
                o4[r] = (short)f2bf(gelu_f(h));
            }
            *(s4v*)(outT + rowb + w*32 + ms*16 + q*4) = o4;
        }
    }
}

// ---------------- fused 1x1-conv (MFMA) + LN + GELU, 512 thr, N=32, Kstage=64 ----------------
__global__ __launch_bounds__(512)
void k_branch1(const unsigned short* __restrict__ A, int K,
               const unsigned short* __restrict__ BT,
               const float* __restrict__ g, const float* __restrict__ beta,
               unsigned short* __restrict__ outT, int outPitch, int colOff){
    int b = blockIdx.y, n0 = blockIdx.x*32;
    const unsigned short* BTb = BT + (long long)b*HW*K;
    __shared__ unsigned short As[256][72];
    __shared__ unsigned short Bs[32][72];
    __shared__ float Psum[8][32], Psq[8][32], Mn[32], Iv[32];
    __shared__ float Gs[256], Bts[256];
    int t = threadIdx.x, w = t>>6, lane = t&63, m = lane&15, q = lane>>4;
    if (t < 256){ Gs[t] = g[t]; Bts[t] = beta[t]; }
    f4v acc[2][2];
    #pragma unroll
    for (int ms = 0; ms < 2; ms++)
        #pragma unroll
        for (int ct = 0; ct < 2; ct++){ f4v z = {0.f,0.f,0.f,0.f}; acc[ms][ct] = z; }
    for (int k0 = 0; k0 < K; k0 += 64){
        __syncthreads();
        {   int r = t>>1, half = t&1;
            const uint4* src = (const uint4*)(A + (long long)r*K + k0 + half*32);
            uint4* dst = (uint4*)&As[r][half*32];
            dst[0]=src[0]; dst[1]=src[1]; dst[2]=src[2]; dst[3]=src[3];
        }
        {   int n = t>>4, ch = t&15;
            *(uint2*)&Bs[n][ch*4] = *(const uint2*)(BTb + (long long)(n0+n)*K + k0 + ch*4);
        }
        __syncthreads();
        #pragma unroll
        for (int ks = 0; ks < 2; ks++){
            s8v bfr[2];
            #pragma unroll
            for (int ct = 0; ct < 2; ct++) bfr[ct] = *(const s8v*)&Bs[ct*16+m][q*8+ks*32];
            #pragma unroll
            for (int ms = 0; ms < 2; ms++){
                s8v afr = *(const s8v*)&As[w*32 + ms*16 + m][q*8+ks*32];
                #pragma unroll
                for (int ct = 0; ct < 2; ct++)
                    acc[ms][ct] = __builtin_amdgcn_mfma_f32_16x16x32_bf16(afr, bfr[ct], acc[ms][ct], 0,0,0);
            }
        }
    }
    __syncthreads();
    ln_epi32(acc, b, n0, w, lane, m, q, t, Gs, Bts, Psum, Psq, Mn, Iv, outT, outPitch, colOff);
}

// ---------------- fused 3x3 dilated conv (MFMA) + LN + GELU, 512 thr, N=32, Kstage=64 ----------------
__global__ __launch_bounds__(512)
void k_branch3(const unsigned short* __restrict__ Wb,
               const unsigned short* __restrict__ BT, int d,
               const float* __restrict__ g, const float* __restrict__ beta,
               unsigned short* __restrict__ outT, int colOff){
    int b = blockIdx.y;
    int y = blockIdx.x >> 1, x0 = (blockIdx.x & 1)*32;
    int n0 = y*64 + x0;
    const unsigned short* BTb = BT + (long long)b*HW*256;
    __shared__ unsigned short As[256][72];
    __shared__ unsigned short Bs[32][72];
    __shared__ float Psum[8][32], Psq[8][32], Mn[32], Iv[32];
    __shared__ float Gs[256], Bts[256];
    int t = threadIdx.x, w = t>>6, lane = t&63, m = lane&15, q = lane>>4;
    if (t < 256){ Gs[t] = g[t]; Bts[t] = beta[t]; }
    f4v acc[2][2];
    #pragma unroll
    for (int ms = 0; ms < 2; ms++)
        #pragma unroll
        for (int ct = 0; ct < 2; ct++){ f4v z = {0.f,0.f,0.f,0.f}; acc[ms][ct] = z; }
    for (int tap = 0; tap < 9; tap++){
        int dy = tap/3 - 1, dx = tap%3 - 1;
        int ys = y + dy*d;
        bool yok = (unsigned)ys < 64u;
        const unsigned short* wtap = Wb + (long long)tap*65536;
        for (int kc = 0; kc < 4; kc++){
            int ci0 = kc*64;
            __syncthreads();
            {   int r = t>>1, half = t&1;
                const uint4* src = (const uint4*)(wtap + (long long)r*256 + ci0 + half*32);
                uint4* dst = (uint4*)&As[r][half*32];
                dst[0]=src[0]; dst[1]=src[1]; dst[2]=src[2]; dst[3]=src[3];
            }
            {   int n = t>>4, ch = t&15;
                int xs = x0 + n + dx*d;
                uint2 v = {0u,0u};
                if (yok && (unsigned)xs < 64u)
                    v = *(const uint2*)(BTb + (long long)(ys*64+xs)*256 + ci0 + ch*4);
                *(uint2*)&Bs[n][ch*4] = v;
            }
            __syncthreads();
            #pragma unroll
            for (int ks = 0; ks < 2; ks++){
                s8v bfr[2];
                #pragma unroll
                for (int ct = 0; ct < 2; ct++) bfr[ct] = *(const s8v*)&Bs[ct*16+m][q*8+ks*32];
                #pragma unroll
                for (int ms = 0; ms < 2; ms++){
                    s8v afr = *(const s8v*)&As[w*32 + ms*16 + m][q*8+ks*32];
                    #pragma unroll
                    for (int ct = 0; ct < 2; ct++)
                        acc[ms][ct] = __builtin_amdgcn_mfma_f32_16x16x32_bf16(afr, bfr[ct], acc[ms][ct], 0,0,0);
                }
            }
        }
    }
    __syncthreads();
    ln_epi32(acc, b, n0, w, lane, m, q, t, Gs, Bts, Psum, Psq, Mn, Iv, outT, 1280, colOff);
}

// ---------------- conv1 (M=128) MFMA, 256 thr, N=32, Kstage=64 ----------------
__global__ __launch_bounds__(256)
void k_conv1m(const unsigned short* __restrict__ A,      // [128][256] bf16
              const unsigned short* __restrict__ BT,     // [b][HW][256] bf16
              const float* __restrict__ bias,
              unsigned short* __restrict__ outT,         // [b][HW][128] bf16
              unsigned short* __restrict__ outC,         // [b][128][HW] bf16 or null
              float* __restrict__ outF){                 // [b][128][HW] f32 or null
    int b = blockIdx.y, n0 = blockIdx.x*32;
    const unsigned short* BTb = BT + (long long)b*HW*256;
    __shared__ unsigned short As[128][72];
    __shared__ unsigned short Bs[32][72];
    int t = threadIdx.x, w = t>>6, lane = t&63, m = lane&15, q = lane>>4;
    f4v acc[2][2];
    #pragma unroll
    for (int ms = 0; ms < 2; ms++)
        #pragma unroll
        for (int ct = 0; ct < 2; ct++){ f4v z = {0.f,0.f,0.f,0.f}; acc[ms][ct] = z; }
    for (int k0 = 0; k0 < 256; k0 += 64){
        __syncthreads();
        {   int r = t>>1, half = t&1;
            const uint4* src = (const uint4*)(A + (long long)r*256 + k0 + half*32);
            uint4* dst = (uint4*)&As[r][half*32];
            dst[0]=src[0]; dst[1]=src[1]; dst[2]=src[2]; dst[3]=src[3];
        }
        {   int n = t>>3, ch = t&7;
            *(uint4*)&Bs[n][ch*8] = *(const uint4*)(BTb + (long long)(n0+n)*256 + k0 + ch*8);
        }
        __syncthreads();
        #pragma unroll
        for (int ks = 0; ks < 2; ks++){
            s8v bfr[2];
            #pragma unroll
            for (int ct = 0; ct < 2; ct++) bfr[ct] = *(const s8v*)&Bs[ct*16+m][q*8+ks*32];
            #pragma unroll
            for (int ms = 0; ms < 2; ms++){
                s8v afr = *(const s8v*)&As[w*32 + ms*16 + m][q*8+ks*32];
                #pragma unroll
                for (int ct = 0; ct < 2; ct++)
                    acc[ms][ct] = __builtin_amdgcn_mfma_f32_16x16x32_bf16(afr, bfr[ct], acc[ms][ct], 0,0,0);
            }
        }
    }
    #pragma unroll
    for (int ct = 0; ct < 2; ct++){
        int p = n0 + ct*16 + m;
        #pragma unroll
        for (int ms = 0; ms < 2; ms++){
            s4v o4;
            float vals[4];
            #pragma unroll
            for (int r = 0; r < 4; r++){
                int c = w*32 + ms*16 + q*4 + r;
                vals[r] = acc[ms][ct][r] + bias[c];
                o4[r] = (short)f2bf(vals[r]);
            }
            *(s4v*)(outT + ((long long)b*HW + p)*128 + w*32 + ms*16 + q*4) = o4;
            if (outC){
                #pragma unroll
                for (int r = 0; r < 4; r++){
                    int c = w*32 + ms*16 + q*4 + r;
                    outC[((long long)b*128 + c)*HW + p] = (unsigned short)o4[r];
                }
            }
            if (outF){
                #pragma unroll
                for (int r = 0; r < 4; r++){
                    int c = w*32 + ms*16 + q*4 + r;
                    outF[((long long)b*128 + c)*HW + p] = vals[r];
                }
            }
        }
    }
}

// ---------------- pooled branch fused with broadcast into catT cols 1024..1279 ----------------
__global__ __launch_bounds__(256)
void k_poolbcast(const float* __restrict__ gp, const float* __restrict__ w,
                 const float* __restrict__ g, const float* __restrict__ bta,
                 unsigned short* __restrict__ catT){
    int b = blockIdx.y, p0 = blockIdx.x*128;
    int t = threadIdx.x;
    __shared__ float z_s[256];
    __shared__ unsigned short bp_s[256];
    __shared__ float stat[2];
    float z = 0.f;
    for (int c = 0; c < 256; c++) z += gp[b*256 + c] * w[t*256 + c];
    z_s[t] = z;
    __syncthreads();
    if (t == 0){
        float s = 0.f, s2 = 0.f;
        for (int c = 0; c < 256; c++){ s += z_s[c]; s2 += z_s[c]*z_s[c]; }
        float mean = s / 256.f, var = s2 / 256.f - mean*mean;
        stat[0] = mean; stat[1] = rsqrtf(var + 1e-6f);
    }
    __syncthreads();
    float h = g[t] * ((z - stat[0]) * stat[1]) + bta[t];
    bp_s[t] = f2bf(gelu_f(h));
    __syncthreads();
    for (int it = 0; it < 16; it++){
        int i = it*256 + t;
        int pl = i >> 5, cj = (i & 31) * 8;
        s8v v8;
        #pragma unroll
        for (int k2 = 0; k2 < 8; k2++) v8[k2] = (short)bp_s[cj + k2];
        *(s8v*)(catT + ((long long)b*HW + p0 + pl)*1280 + 1024 + cj) = v8;
    }
}

// ---------------- attention pass 1 (split-j, dbuf LDS Ps, global Q frags) ----------------
__global__ __launch_bounds__(256)
void k_attn_stats2(const unsigned short* __restrict__ QT,
                   const unsigned short* __restrict__ PT,
                   float* __restrict__ mpart, float* __restrict__ lpart){
    int b = blockIdx.z, jc = blockIdx.y, k0 = blockIdx.x * 64;
    const unsigned short* QTb = QT + (long long)b * HW * CO;
    const unsigned short* PTb = PT + (long long)b * HW * CO;
    __shared__ unsigned short Ps[2][64][132];
    int t = threadIdx.x;
    int w = t >> 6, lane = t & 63, m = lane & 15, q = lane >> 4;
    s8v a[4];
    #pragma unroll
    for (int ks = 0; ks < 4; ks++)
        a[ks] = *(const s8v*)(QTb + (long long)(k0 + w*16 + m) * CO + q*8 + ks*32);
    float rm[4], rl[4];
    #pragma unroll
    for (int r = 0; r < 4; r++){ rm[r] = -1e30f; rl[r] = 0.f; }
    const float scale = 0.015625f;           // 1/sqrt(4096)
    int jbase = jc * 1024;
    int sr = t >> 2, sch = t & 3;
    uint4 pf[4];
    {   const uint4* src = (const uint4*)(PTb + (long long)(jbase + sr) * CO + sch * 32);
        #pragma unroll
        for (int i = 0; i < 4; i++) pf[i] = src[i];
    }
    for (int jt = 0; jt < 16; jt++){
        int cur = jt & 1;
        {   uint4* dst = (uint4*)&Ps[cur][sr][sch * 32];
            #pragma unroll
            for (int i = 0; i < 4; i++) dst[i] = pf[i];
        }
        __syncthreads();
        if (jt < 15){
            const uint4* src = (const uint4*)(PTb + (long long)(jbase + (jt+1)*64 + sr) * CO + sch * 32);
            #pragma unroll
            for (int i = 0; i < 4; i++) pf[i] = src[i];
        }
        float sv[4][4];
        #pragma unroll
        for (int ct = 0; ct < 4; ct++){
            f4v acc = {0.f,0.f,0.f,0.f};
            #pragma unroll
            for (int ks = 0; ks < 4; ks++){
                s8v bv = *(const s8v*)&Ps[cur][ct*16 + m][q*8 + ks*32];
                acc = __builtin_amdgcn_mfma_f32_16x16x32_bf16(a[ks], bv, acc, 0, 0, 0);
            }
            #pragma unroll
            for (int r = 0; r < 4; r++) sv[ct][r] = acc[r] * scale;
        }
        #pragma unroll
        for (int r = 0; r < 4; r++){
            float mx = fmaxf(fmaxf(sv[0][r], sv[1][r]), fmaxf(sv[2][r], sv[3][r]));
            #pragma unroll
            for (int msk = 1; msk < 16; msk <<= 1) mx = fmaxf(mx, __shfl_xor(mx, msk));
            float nm = fmaxf(rm[r], mx);
            float se = __expf(sv[0][r]-nm) + __expf(sv[1][r]-nm)
                     + __expf(sv[2][r]-nm) + __expf(sv[3][r]-nm);
            #pragma unroll
            for (int msk = 1; msk < 16; msk <<= 1) se += __shfl_xor(se, msk);
            rl[r] = rl[r] * __expf(rm[r] - nm) + se;
            rm[r] = nm;
        }
    }
    if (m == 0){
        #pragma unroll
        for (int r = 0; r < 4; r++){
            int k = k0 + w*16 + q*4 + r;
            long long idx = (long long)jc * (NB*HW) + (long long)b*HW + k;
            mpart[idx] = rm[r];
            lpart[idx] = rl[r];
        }
    }
}

// ---------------- combine partial softmax stats ----------------
__global__ void k_attn_comb(const float* __restrict__ mpart, const float* __restrict__ lpart,
                            float* __restrict__ mrow, float* __restrict__ ilrow){
    int i = blockIdx.x*256 + threadIdx.x;
    float m0 = mpart[i], m1 = mpart[i+16384], m2 = mpart[i+32768], m3 = mpart[i+49152];
    float m = fmaxf(fmaxf(m0,m1), fmaxf(m2,m3));
    float l = lpart[i]*__expf(m0-m) + lpart[i+16384]*__expf(m1-m)
            + lpart[i+32768]*__expf(m2-m) + lpart[i+49152]*__expf(m3-m);
    mrow[i] = m;
    ilrow[i] = 1.f / l;
}

// ---------------- attention pass 2 (split-k): R4-exact 79us version ----------------
__global__ __launch_bounds__(256)
void k_attn_apply2(const unsigned short* __restrict__ QT,
                   const unsigned short* __restrict__ PT,
                   const unsigned short* __restrict__ Pb,
                   const float* __restrict__ mrow, const float* __restrict__ ilrow,
                   float* __restrict__ Lp){
    int b = blockIdx.z, kc = blockIdx.y, j0 = blockIdx.x * 64;
    const unsigned short* QTb = QT + (long long)b * HW * CO;
    const unsigned short* PTb = PT + (long long)b * HW * CO;
    const unsigned short* Pbb = Pb + (long long)b * CO * HW;
    const float* mb = mrow + (long long)b * HW;
    const float* lb = ilrow + (long long)b * HW;
    __shared__ unsigned short Qks[64][136];  // also Pjs during init (aliased)
    __shared__ unsigned short Pcs[128][72];
    __shared__ unsigned short Et[64][72];
    int t = threadIdx.x;
    int w = t >> 6, lane = t & 63, m = lane & 15, q = lane >> 4;
    {   // stage PT j-tile into Qks slot, read bj frags to registers
        int r = t >> 2, ch = t & 3;
        const uint4* src = (const uint4*)(PTb + (long long)(j0 + r) * CO + ch * 32);
        uint4* dst = (uint4*)&Qks[r][ch * 32];
        #pragma unroll
        for (int i = 0; i < 4; i++) dst[i] = src[i];
    }
    __syncthreads();
    s8v bj[4][4];
    #pragma unroll
    for (int ct = 0; ct < 4; ct++)
        #pragma unroll
        for (int ks = 0; ks < 4; ks++)
            bj[ct][ks] = *(const s8v*)&Qks[ct*16 + m][q*8 + ks*32];
    f4v accL[2][4];
    #pragma unroll
    for (int mt = 0; mt < 2; mt++)
        #pragma unroll
        for (int ct = 0; ct < 4; ct++){ f4v z = {0.f,0.f,0.f,0.f}; accL[mt][ct] = z; }
    const float scale = 0.015625f;
    int kbase = kc * 1024;
    for (int kt = 0; kt < 16; kt++){
        int k0 = kbase + kt*64;
        __syncthreads();
        {
            int r = t >> 2, ch = t & 3;
            const uint4* src = (const uint4*)(QTb + (long long)(k0 + r) * CO + ch * 32);
            uint4* dst = (uint4*)&Qks[r][ch * 32];
            #pragma unroll
            for (int i = 0; i < 4; i++) dst[i] = src[i];
        }
        {
            int c = t >> 1, hf = t & 1;
            const uint4* src = (const uint4*)(Pbb + (long long)c * HW + k0 + hf * 32);
            uint4* dst = (uint4*)&Pcs[c][hf * 32];
            #pragma unroll
            for (int i = 0; i < 4; i++) dst[i] = src[i];
        }
        __syncthreads();
        s8v aS[4];
        #pragma unroll
        for (int ks = 0; ks < 4; ks++) aS[ks] = *(const s8v*)&Qks[w*16 + m][q*8 + ks*32];
        float mk[4], il[4];
        #pragma unroll
        for (int r = 0; r < 4; r++){
            int kg = k0 + w*16 + q*4 + r;
            mk[r] = mb[kg]; il[r] = lb[kg];
        }
        #pragma unroll
        for (int ct = 0; ct < 4; ct++){
            f4v s = {0.f,0.f,0.f,0.f};
            #pragma unroll
            for (int ks = 0; ks < 4; ks++)
                s = __builtin_amdgcn_mfma_f32_16x16x32_bf16(aS[ks], bj[ct][ks], s, 0, 0, 0);
            s4v e4;
            #pragma unroll
            for (int r = 0; r < 4; r++)
                e4[r] = (short)f2bf(__expf(s[r]*scale - mk[r]) * il[r]);
            *(s4v*)&Et[ct*16 + m][w*16 + q*4] = e4;
        }
        __syncthreads();
        s8v aP[2][2];
        #pragma unroll
        for (int mt = 0; mt < 2; mt++)
            #pragma unroll
            for (int ks2 = 0; ks2 < 2; ks2++)
                aP[mt][ks2] = *(const s8v*)&Pcs[w*32 + mt*16 + m][q*8 + ks2*32];
        #pragma unroll
        for (int ct = 0; ct < 4; ct++){
            s8v bE0 = *(const s8v*)&Et[ct*16 + m][q*8];
            s8v bE1 = *(const s8v*)&Et[ct*16 + m][q*8 + 32];
            #pragma unroll
            for (int mt = 0; mt < 2; mt++){
                accL[mt][ct] = __builtin_amdgcn_mfma_f32_16x16x32_bf16(aP[mt][0], bE0, accL[mt][ct], 0, 0, 0);
                accL[mt][ct] = __builtin_amdgcn_mfma_f32_16x16x32_bf16(aP[mt][1], bE1, accL[mt][ct], 0, 0, 0);
            }
        }
    }
    float* Lpb = Lp + ((long long)(kc*NB + b) * CO) * HW;
    #pragma unroll
    for (int mt = 0; mt < 2; mt++)
        #pragma unroll
        for (int ct = 0; ct < 4; ct++)
            #pragma unroll
            for (int r = 0; r < 4; r++){
                int c = w*32 + mt*16 + q*4 + r;
                Lpb[(long long)c*HW + j0 + ct*16 + m] = accL[mt][ct][r];
            }
}

// ---------------- fused: O = xa + sum(Lp) -> bf16 B-tile -> conv2 -> out f32 ----------------
__global__ __launch_bounds__(256)
void k_outfused(const unsigned short* __restrict__ A,    // w_c2 [256][128] bf16
                const float* __restrict__ Lp, const float* __restrict__ xa,
                const float* __restrict__ bias, float* __restrict__ out){
    int b = blockIdx.y, j0 = blockIdx.x*32;
    __shared__ unsigned short Bs[32][136];
    __shared__ __align__(16) char pool[256*68*2];   // phase1: Bsf[128][33] f32; phase2: As[256][68] bf16
    int t = threadIdx.x;
    // phase 1: O tile f32 = xa + 4 partials (coalesced c-rows)
    {
        float* Bsf = (float*)pool;
        int c = t>>1, jh = t&1;
        long long base = ((long long)b*CO + c)*HW + j0 + jh*16;
        const long long csz = (long long)NB*CO*HW;
        float v[16];
        #pragma unroll
        for (int r = 0; r < 16; r++) v[r] = xa[base + r];
        #pragma unroll
        for (int pidx = 0; pidx < 4; pidx++){
            const float* src = Lp + pidx*csz + base;
            #pragma unroll
            for (int r = 0; r < 16; r++) v[r] += src[r];
        }
        #pragma unroll
        for (int r = 0; r < 16; r++) Bsf[c*33 + jh*16 + r] = v[r];
    }
    __syncthreads();
    // transpose to bf16 B-tile [j][c]
    {
        const float* Bsf = (const float*)pool;
        int j = t>>3, cs = t&7;
        #pragma unroll
        for (int r = 0; r < 16; r++){
            int c = cs*16 + r;
            Bs[j][c] = f2bf(Bsf[c*33 + j]);
        }
    }
    __syncthreads();
    // phase 2: GEMM M=256 x N=32 x K=128
    unsigned short (*As)[68] = (unsigned short(*)[68])pool;
    int w = t>>6, lane = t&63, m = lane&15, q = lane>>4;
    f4v acc[4][2];
    #pragma unroll
    for (int ms = 0; ms < 4; ms++)
        #pragma unroll
        for (int ct = 0; ct < 2; ct++){ f4v z = {0.f,0.f,0.f,0.f}; acc[ms][ct] = z; }
    for (int k0 = 0; k0 < 128; k0 += 64){
        __syncthreads();
        {   const uint4* src = (const uint4*)(A + (long long)t*128 + k0);
            uint4* dst = (uint4*)&As[t][0];
            #pragma unroll
            for (int i = 0; i < 8; i++) dst[i] = src[i];
        }
        __syncthreads();
        #pragma unroll
        for (int ks = 0; ks < 2; ks++){
            s8v bfr[2];
            #pragma unroll
            for (int ct = 0; ct < 2; ct++) bfr[ct] = *(const s8v*)&Bs[ct*16+m][k0 + ks*32 + q*8];
            #pragma unroll
            for (int ms = 0; ms < 4; ms++){
                s8v afr = *(const s8v*)&As[w*64 + ms*16 + m][q*8 + ks*32];
                #pragma unroll
                for (int ct = 0; ct < 2; ct++)
                    acc[ms][ct] = __builtin_amdgcn_mfma_f32_16x16x32_bf16(afr, bfr[ct], acc[ms][ct], 0,0,0);
            }
        }
    }
    #pragma unroll
    for (int ct = 0; ct < 2; ct++){
        int p = j0 + ct*16 + m;
        #pragma unroll
        for (int ms = 0; ms < 4; ms++)
            #pragma unroll
            for (int r = 0; r < 4; r++){
                int c = w*64 + ms*16 + q*4 + r;
                out[((long long)b*256 + c)*HW + p] = acc[ms][ct][r] + bias[c];
            }
    }
}

extern "C" void kernel_launch(void* const* d_in, const int* in_sizes, int n_in,
                              void* d_out, int out_size, void* d_ws, size_t ws_size,
                              hipStream_t stream) {
    const float* x       = (const float*)d_in[0];
    const float* conv1_w = (const float*)d_in[1];
    const float* conv1_b = (const float*)d_in[2];
    const float* conv2_w = (const float*)d_in[3];
    const float* conv2_b = (const float*)d_in[4];
    const float* cw_w1   = (const float*)d_in[5];
    const float* cw_b1   = (const float*)d_in[6];
    const float* cw_g    = (const float*)d_in[7];
    const float* cw_bt   = (const float*)d_in[8];
    const float* cw_w2   = (const float*)d_in[9];
    const float* cw_b2   = (const float*)d_in[10];
    const float* a0_w    = (const float*)d_in[11];
    const float* a0_g    = (const float*)d_in[12];
    const float* a0_b    = (const float*)d_in[13];
    const float* a1_w    = (const float*)d_in[14];
    const float* a1_g    = (const float*)d_in[15];
    const float* a1_b    = (const float*)d_in[16];
    const float* a2_w    = (const float*)d_in[17];
    const float* a2_g    = (const float*)d_in[18];
    const float* a2_b    = (const float*)d_in[19];
    const float* a3_w    = (const float*)d_in[20];
    const float* a3_g    = (const float*)d_in[21];
    const float* a3_b    = (const float*)d_in[22];
    const float* ap_w    = (const float*)d_in[23];
    const float* ap_g    = (const float*)d_in[24];
    const float* ap_b    = (const float*)d_in[25];
    const float* pj_w    = (const float*)d_in[26];
    const float* pj_g    = (const float*)d_in[27];
    const float* pj_b    = (const float*)d_in[28];
    float* out = (float*)d_out;

    // ---- workspace layout ----
    float* ws    = (float*)d_ws;
    float* avg   = ws;                  // 1024
    float* mx    = ws + 1024;           // 1024
    float* sv    = ws + 2048;           // 1024
    float* gp    = ws + 3072;           // 1024
    float* mrow  = ws + 5120;           // 16384
    float* ilrow = ws + 21504;          // 16384
    float* xa    = ws + 37888;          // 2,097,152
    float* mpart = xa + 2097152;        // 65536
    float* lpart = mpart + 65536;       // 65536
    unsigned short* sb = (unsigned short*)(ws + 4232192);
    unsigned short* xT    = sb;                    // 4,194,304
    unsigned short* xcT   = sb + 4194304;          // 4,194,304
    unsigned short* catT  = sb + 8388608;          // 20,971,520
    unsigned short* projT = sb + 29360128;         // 4,194,304
    unsigned short* P_bf  = sb + 33554432;         // 2,097,152
    unsigned short* PT_bf = sb + 35651584;         // 2,097,152
    unsigned short* QT_bf = sb + 37748736;         // 2,097,152
    unsigned short* w_c1  = sb + 41943040;         // 32768
    unsigned short* w_a0  = sb + 41975808;         // 65536
    unsigned short* w_pj  = sb + 42041344;         // 327680
    unsigned short* w_c2  = sb + 42369024;         // 32768
    unsigned short* w_d3  = sb + 42401792;         // 589824
    unsigned short* w_d6  = sb + 42991616;         // 589824
    unsigned short* w_d9  = sb + 43581440;         // 589824
    float* Lp = (float*)catT;           // alias: catT dead after proj (33.5MB in 42MB region)

    // ---- stats + channel weighting ----
    k_rowstats<<<dim3(NB*CI), 256, 0, stream>>>(x, avg, mx);
    k_cw<<<dim3(NB), 256, 0, stream>>>(avg, mx, cw_w1, cw_b1, cw_g, cw_bt, cw_w2, cw_b2, sv, gp);

    // ---- all weight casts (one launch) ----
    k_allcast<<<dim3(8704), 256, 0, stream>>>(conv1_w, a0_w, pj_w, conv2_w, a1_w, a2_w, a3_w,
                                              w_c1, w_a0, w_pj, w_c2, w_d3, w_d6, w_d9);

    // ---- x -> xT bf16 and xcT ----
    k_xT<<<dim3(64, 4, NB), 256, 0, stream>>>(x, sv, xT, xcT);

    // ---- x1 = conv1(x)+b -> P_bf/PT_bf ----
    k_conv1m<<<dim3(128, NB), 256, 0, stream>>>(w_c1, xT, conv1_b, PT_bf, P_bf, nullptr);

    // ---- ASPP branches (fused conv+LN+GELU -> catT bf16) ----
    k_branch1<<<dim3(128, NB), 512, 0, stream>>>(w_a0, 256, xcT, a0_g, a0_b, catT, 1280, 0);
    k_branch3<<<dim3(128, NB), 512, 0, stream>>>(w_d3, xcT, 3, a1_g, a1_b, catT, 256);
    k_branch3<<<dim3(128, NB), 512, 0, stream>>>(w_d6, xcT, 6, a2_g, a2_b, catT, 512);
    k_branch3<<<dim3(128, NB), 512, 0, stream>>>(w_d9, xcT, 9, a3_g, a3_b, catT, 768);
    k_poolbcast<<<dim3(32, NB), 256, 0, stream>>>(gp, ap_w, ap_g, ap_b, catT);

    // ---- proj = GELU(LN(conv1x1(cat))) -> projT bf16 ----
    k_branch1<<<dim3(128, NB), 512, 0, stream>>>(w_pj, 1280, catT, pj_g, pj_b, projT, 256, 0);

    // ---- xa = conv1(proj)+b -> xa f32 + QT_bf ----
    k_conv1m<<<dim3(128, NB), 256, 0, stream>>>(w_c1, projT, conv1_b, QT_bf, nullptr, xa);

    // ---- attention (R4-exact apply2 + separate comb) ----
    k_attn_stats2<<<dim3(64, 4, NB), 256, 0, stream>>>(QT_bf, PT_bf, mpart, lpart);
    k_attn_comb<<<dim3(64), 256, 0, stream>>>(mpart, lpart, mrow, ilrow);
    k_attn_apply2<<<dim3(64, 4, NB), 256, 0, stream>>>(QT_bf, PT_bf, P_bf, mrow, ilrow, Lp);

    // ---- out = conv2(xa + sum Lp) + b (fused) ----
    k_outfused<<<dim3(128, NB), 256, 0, stream>>>(w_c2, Lp, xa, conv2_b, out);

    (void)in_sizes; (void)n_in; (void)out_size; (void)ws_size;
}

// Round 9
// 536.652 us; speedup vs baseline: 1.1721x; 1.0658x over previous
//
#include <hip/hip_runtime.h>
#include <hip/hip_bf16.h>
#include <math.h>

// Problem constants (B=4, Cin=256, Cout=128, H=W=64)
#define NB 4
#define CI 256
#define CO 128
#define HW 4096

typedef __attribute__((ext_vector_type(8))) short s8v;   // 8 bf16 = 4 VGPRs (MFMA A/B frag)
typedef __attribute__((ext_vector_type(4))) short s4v;
typedef __attribute__((ext_vector_type(4))) float f4v;   // MFMA C/D frag

__device__ __forceinline__ unsigned short f2bf(float f){
    __hip_bfloat16 h = __float2bfloat16(f);   // RNE
    return *reinterpret_cast<unsigned short*>(&h);
}

// A&S 7.1.26 erf (max abs err 1.5e-7)
__device__ __forceinline__ float gelu_f(float x){
    float z  = x * 0.70710678118654752f;
    float az = fabsf(z);
    float tt = 1.f / (1.f + 0.3275911f * az);
    float poly = tt*(0.254829592f + tt*(-0.284496736f + tt*(1.421413741f +
                 tt*(-1.453152027f + tt*1.061405429f))));
    float erfv = 1.f - poly * __expf(-az*az);
    erfv = (z < 0.f) ? -erfv : erfv;
    return 0.5f * x * (1.f + erfv);
}

// ---------------- per-channel avg/max over HW ----------------
__global__ void k_rowstats(const float* __restrict__ x, float* __restrict__ avg, float* __restrict__ mx){
    int row = blockIdx.x;
    const float* p = x + (long long)row * HW;
    int t = threadIdx.x;
    float s = 0.f, m = -1e30f;
    for (int i = t; i < HW; i += 256){ float v = p[i]; s += v; m = fmaxf(m, v); }
    __shared__ float ss[256], sm[256];
    ss[t] = s; sm[t] = m; __syncthreads();
    for (int o = 128; o > 0; o >>= 1){
        if (t < o){ ss[t] += ss[t+o]; sm[t] = fmaxf(sm[t], sm[t+o]); }
        __syncthreads();
    }
    if (t == 0){ avg[row] = ss[0] / (float)HW; mx[row] = sm[0]; }
}

// ---------------- ChannelWeighting; also gp = avg*(1+s) ----------------
__global__ void k_cw(const float* __restrict__ avg, const float* __restrict__ mx,
                     const float* __restrict__ w1, const float* __restrict__ b1,
                     const float* __restrict__ lng, const float* __restrict__ lnb,
                     const float* __restrict__ w2, const float* __restrict__ b2,
                     float* __restrict__ sv, float* __restrict__ gp){
    int b = blockIdx.x, t = threadIdx.x;
    __shared__ float o_s[256];
    __shared__ float h_s[128];
    __shared__ float stat[2];
    float a = avg[b*256 + t];
    o_s[t] = fabsf(a - mx[b*256 + t]) * a;
    __syncthreads();
    if (t < 128){
        float h = b1[t];
        for (int i = 0; i < 256; i++) h += o_s[i] * w1[t*256 + i];
        h_s[t] = h;
    }
    __syncthreads();
    if (t == 0){
        float s = 0.f, s2 = 0.f;
        for (int j = 0; j < 128; j++){ s += h_s[j]; s2 += h_s[j]*h_s[j]; }
        float mean = s / 128.f;
        float var  = s2 / 128.f - mean*mean;
        stat[0] = mean; stat[1] = rsqrtf(var + 1e-5f);
    }
    __syncthreads();
    if (t < 128) h_s[t] = lng[t] * ((h_s[t] - stat[0]) * stat[1]) + lnb[t];
    __syncthreads();
    float z = b2[t];
    for (int j = 0; j < 128; j++) z += h_s[j] * w2[t*128 + j];
    float sig = 1.f / (1.f + __expf(-z));
    sv[b*256 + t] = sig;
    gp[b*256 + t] = a * (1.f + sig);
}

// ---------------- ALL weight casts in one launch ----------------
__global__ void k_allcast(const float* __restrict__ c1, const float* __restrict__ a0,
                          const float* __restrict__ pj, const float* __restrict__ c2,
                          const float* __restrict__ d3, const float* __restrict__ d6,
                          const float* __restrict__ d9,
                          unsigned short* __restrict__ w_c1, unsigned short* __restrict__ w_a0,
                          unsigned short* __restrict__ w_pj, unsigned short* __restrict__ w_c2,
                          unsigned short* __restrict__ w_d3, unsigned short* __restrict__ w_d6,
                          unsigned short* __restrict__ w_d9){
    int i = blockIdx.x*256 + threadIdx.x;
    if (i < 458752){
        if (i < 32768)        w_c1[i]        = f2bf(c1[i]);
        else if (i < 98304)   w_a0[i-32768]  = f2bf(a0[i-32768]);
        else if (i < 425984)  w_pj[i-98304]  = f2bf(pj[i-98304]);
        else                  w_c2[i-425984] = f2bf(c2[i-425984]);
    } else {
        int j = i - 458752;
        int which = j / 589824;
        int l = j - which*589824;
        int tap = l >> 16, rem = l & 65535, o = rem >> 8, ci = rem & 255;
        const float* src = (which==0) ? d3 : ((which==1) ? d6 : d9);
        unsigned short* dst = (which==0) ? w_d3 : ((which==1) ? w_d6 : w_d9);
        dst[l] = f2bf(src[o*2304 + ci*9 + tap]);
    }
}

// ---------------- x -> xT bf16 [b][HW][256] and xcT = bf16(x*(1+s)) ----------------
__global__ void k_xT(const float* __restrict__ x, const float* __restrict__ sv,
                     unsigned short* __restrict__ xT, unsigned short* __restrict__ xcT){
    int b = blockIdx.z, c0 = blockIdx.y*64, h0 = blockIdx.x*64;
    __shared__ unsigned short T1[64][66], T2[64][66];
    int t = threadIdx.x;
    int hl = t & 63, cs = t >> 6;
    #pragma unroll
    for (int r = 0; r < 16; r++){
        int c = cs*16 + r;
        float v = x[((long long)b*256 + c0 + c)*HW + h0 + hl];
        float sc = 1.f + sv[b*256 + c0 + c];
        T1[c][hl] = f2bf(v);
        T2[c][hl] = f2bf(v*sc);
    }
    __syncthreads();
    int cl = t & 63, hs = t >> 6;
    #pragma unroll
    for (int r = 0; r < 16; r++){
        int h = hs*16 + r;
        long long o = ((long long)b*HW + h0 + h)*256 + c0 + cl;
        xT[o]  = T1[cl][h];
        xcT[o] = T2[cl][h];
    }
}

// ============ 8-wave epilogue, N=32: LN(256ch)+GELU -> transposed bf16 ============
__device__ __forceinline__ void ln_epi32(f4v acc[2][2],
        int b, int n0, int w, int lane, int m, int q, int t,
        const float* Gs, const float* Bts,
        float (*Psum)[32], float (*Psq)[32], float* Mn, float* Iv,
        unsigned short* __restrict__ outT, int outPitch, int colOff){
    float ls[2], ls2[2];
    #pragma unroll
    for (int ct = 0; ct < 2; ct++){
        float s = 0.f, s2 = 0.f;
        #pragma unroll
        for (int ms = 0; ms < 2; ms++)
            #pragma unroll
            for (int r = 0; r < 4; r++){ float v = acc[ms][ct][r]; s += v; s2 += v*v; }
        ls[ct] = s; ls2[ct] = s2;
    }
    #pragma unroll
    for (int ct = 0; ct < 2; ct++){
        ls[ct]  += __shfl_xor(ls[ct], 16);  ls[ct]  += __shfl_xor(ls[ct], 32);
        ls2[ct] += __shfl_xor(ls2[ct], 16); ls2[ct] += __shfl_xor(ls2[ct], 32);
    }
    if (lane < 16){
        #pragma unroll
        for (int ct = 0; ct < 2; ct++){ Psum[w][ct*16+lane] = ls[ct]; Psq[w][ct*16+lane] = ls2[ct]; }
    }
    __syncthreads();
    if (t < 32){
        float s = 0.f, s2 = 0.f;
        #pragma unroll
        for (int ww = 0; ww < 8; ww++){ s += Psum[ww][t]; s2 += Psq[ww][t]; }
        float mean = s * (1.f/256.f);
        Mn[t] = mean;
        Iv[t] = rsqrtf(s2*(1.f/256.f) - mean*mean + 1e-6f);
    }
    __syncthreads();
    #pragma unroll
    for (int ct = 0; ct < 2; ct++){
        int p = ct*16 + m;
        float mean = Mn[p], inv = Iv[p];
        long long rowb = ((long long)b*HW + n0 + p)*outPitch + colOff;
        #pragma unroll
        for (int ms = 0; ms < 2; ms++){
            s4v o4;
            #pragma unroll
            for (int r = 0; r < 4; r++){
                int c = w*32 + ms*16 + q*4 + r;
                float h = Gs[c]*((acc[ms][ct][r] - mean)*inv) + Bts[c];
                o4[r] = (short)f2bf(gelu_f(h));
            }
            *(s4v*)(outT + rowb + w*32 + ms*16 + q*4) = o4;
        }
    }
}

// ---------------- fused 1x1-conv (MFMA) + LN + GELU, 512 thr, N=32, Kstage=64 ----------------
__global__ __launch_bounds__(512)
void k_branch1(const unsigned short* __restrict__ A, int K,
               const unsigned short* __restrict__ BT,
               const float* __restrict__ g, const float* __restrict__ beta,
               unsigned short* __restrict__ outT, int outPitch, int colOff){
    int b = blockIdx.y, n0 = blockIdx.x*32;
    const unsigned short* BTb = BT + (long long)b*HW*K;
    __shared__ unsigned short As[256][72];
    __shared__ unsigned short Bs[32][72];
    __shared__ float Psum[8][32], Psq[8][32], Mn[32], Iv[32];
    __shared__ float Gs[256], Bts[256];
    int t = threadIdx.x, w = t>>6, lane = t&63, m = lane&15, q = lane>>4;
    if (t < 256){ Gs[t] = g[t]; Bts[t] = beta[t]; }
    f4v acc[2][2];
    #pragma unroll
    for (int ms = 0; ms < 2; ms++)
        #pragma unroll
        for (int ct = 0; ct < 2; ct++){ f4v z = {0.f,0.f,0.f,0.f}; acc[ms][ct] = z; }
    for (int k0 = 0; k0 < K; k0 += 64){
        __syncthreads();
        {   int r = t>>1, half = t&1;
            const uint4* src = (const uint4*)(A + (long long)r*K + k0 + half*32);
            uint4* dst = (uint4*)&As[r][half*32];
            dst[0]=src[0]; dst[1]=src[1]; dst[2]=src[2]; dst[3]=src[3];
        }
        {   int n = t>>4, ch = t&15;
            *(uint2*)&Bs[n][ch*4] = *(const uint2*)(BTb + (long long)(n0+n)*K + k0 + ch*4);
        }
        __syncthreads();
        #pragma unroll
        for (int ks = 0; ks < 2; ks++){
            s8v bfr[2];
            #pragma unroll
            for (int ct = 0; ct < 2; ct++) bfr[ct] = *(const s8v*)&Bs[ct*16+m][q*8+ks*32];
            #pragma unroll
            for (int ms = 0; ms < 2; ms++){
                s8v afr = *(const s8v*)&As[w*32 + ms*16 + m][q*8+ks*32];
                #pragma unroll
                for (int ct = 0; ct < 2; ct++)
                    acc[ms][ct] = __builtin_amdgcn_mfma_f32_16x16x32_bf16(afr, bfr[ct], acc[ms][ct], 0,0,0);
            }
        }
    }
    __syncthreads();
    ln_epi32(acc, b, n0, w, lane, m, q, t, Gs, Bts, Psum, Psq, Mn, Iv, outT, outPitch, colOff);
}

// ---------------- fused 3x3 dilated conv (MFMA) + LN + GELU, 512 thr, N=32, Kstage=64 ----------------
__global__ __launch_bounds__(512)
void k_branch3(const unsigned short* __restrict__ Wb,
               const unsigned short* __restrict__ BT, int d,
               const float* __restrict__ g, const float* __restrict__ beta,
               unsigned short* __restrict__ outT, int colOff){
    int b = blockIdx.y;
    int y = blockIdx.x >> 1, x0 = (blockIdx.x & 1)*32;
    int n0 = y*64 + x0;
    const unsigned short* BTb = BT + (long long)b*HW*256;
    __shared__ unsigned short As[256][72];
    __shared__ unsigned short Bs[32][72];
    __shared__ float Psum[8][32], Psq[8][32], Mn[32], Iv[32];
    __shared__ float Gs[256], Bts[256];
    int t = threadIdx.x, w = t>>6, lane = t&63, m = lane&15, q = lane>>4;
    if (t < 256){ Gs[t] = g[t]; Bts[t] = beta[t]; }
    f4v acc[2][2];
    #pragma unroll
    for (int ms = 0; ms < 2; ms++)
        #pragma unroll
        for (int ct = 0; ct < 2; ct++){ f4v z = {0.f,0.f,0.f,0.f}; acc[ms][ct] = z; }
    for (int tap = 0; tap < 9; tap++){
        int dy = tap/3 - 1, dx = tap%3 - 1;
        int ys = y + dy*d;
        bool yok = (unsigned)ys < 64u;
        const unsigned short* wtap = Wb + (long long)tap*65536;
        for (int kc = 0; kc < 4; kc++){
            int ci0 = kc*64;
            __syncthreads();
            {   int r = t>>1, half = t&1;
                const uint4* src = (const uint4*)(wtap + (long long)r*256 + ci0 + half*32);
                uint4* dst = (uint4*)&As[r][half*32];
                dst[0]=src[0]; dst[1]=src[1]; dst[2]=src[2]; dst[3]=src[3];
            }
            {   int n = t>>4, ch = t&15;
                int xs = x0 + n + dx*d;
                uint2 v = {0u,0u};
                if (yok && (unsigned)xs < 64u)
                    v = *(const uint2*)(BTb + (long long)(ys*64+xs)*256 + ci0 + ch*4);
                *(uint2*)&Bs[n][ch*4] = v;
            }
            __syncthreads();
            #pragma unroll
            for (int ks = 0; ks < 2; ks++){
                s8v bfr[2];
                #pragma unroll
                for (int ct = 0; ct < 2; ct++) bfr[ct] = *(const s8v*)&Bs[ct*16+m][q*8+ks*32];
                #pragma unroll
                for (int ms = 0; ms < 2; ms++){
                    s8v afr = *(const s8v*)&As[w*32 + ms*16 + m][q*8+ks*32];
                    #pragma unroll
                    for (int ct = 0; ct < 2; ct++)
                        acc[ms][ct] = __builtin_amdgcn_mfma_f32_16x16x32_bf16(afr, bfr[ct], acc[ms][ct], 0,0,0);
                }
            }
        }
    }
    __syncthreads();
    ln_epi32(acc, b, n0, w, lane, m, q, t, Gs, Bts, Psum, Psq, Mn, Iv, outT, 1280, colOff);
}

// ---------------- conv1 (M=128) MFMA, 256 thr, N=32, Kstage=64 ----------------
__global__ __launch_bounds__(256)
void k_conv1m(const unsigned short* __restrict__ A,      // [128][256] bf16
              const unsigned short* __restrict__ BT,     // [b][HW][256] bf16
              const float* __restrict__ bias,
              unsigned short* __restrict__ outT,         // [b][HW][128] bf16
              unsigned short* __restrict__ outC,         // [b][128][HW] bf16 or null
              float* __restrict__ outF){                 // [b][128][HW] f32 or null
    int b = blockIdx.y, n0 = blockIdx.x*32;
    const unsigned short* BTb = BT + (long long)b*HW*256;
    __shared__ unsigned short As[128][72];
    __shared__ unsigned short Bs[32][72];
    int t = threadIdx.x, w = t>>6, lane = t&63, m = lane&15, q = lane>>4;
    f4v acc[2][2];
    #pragma unroll
    for (int ms = 0; ms < 2; ms++)
        #pragma unroll
        for (int ct = 0; ct < 2; ct++){ f4v z = {0.f,0.f,0.f,0.f}; acc[ms][ct] = z; }
    for (int k0 = 0; k0 < 256; k0 += 64){
        __syncthreads();
        {   int r = t>>1, half = t&1;
            const uint4* src = (const uint4*)(A + (long long)r*256 + k0 + half*32);
            uint4* dst = (uint4*)&As[r][half*32];
            dst[0]=src[0]; dst[1]=src[1]; dst[2]=src[2]; dst[3]=src[3];
        }
        {   int n = t>>3, ch = t&7;
            *(uint4*)&Bs[n][ch*8] = *(const uint4*)(BTb + (long long)(n0+n)*256 + k0 + ch*8);
        }
        __syncthreads();
        #pragma unroll
        for (int ks = 0; ks < 2; ks++){
            s8v bfr[2];
            #pragma unroll
            for (int ct = 0; ct < 2; ct++) bfr[ct] = *(const s8v*)&Bs[ct*16+m][q*8+ks*32];
            #pragma unroll
            for (int ms = 0; ms < 2; ms++){
                s8v afr = *(const s8v*)&As[w*32 + ms*16 + m][q*8+ks*32];
                #pragma unroll
                for (int ct = 0; ct < 2; ct++)
                    acc[ms][ct] = __builtin_amdgcn_mfma_f32_16x16x32_bf16(afr, bfr[ct], acc[ms][ct], 0,0,0);
            }
        }
    }
    #pragma unroll
    for (int ct = 0; ct < 2; ct++){
        int p = n0 + ct*16 + m;
        #pragma unroll
        for (int ms = 0; ms < 2; ms++){
            s4v o4;
            float vals[4];
            #pragma unroll
            for (int r = 0; r < 4; r++){
                int c = w*32 + ms*16 + q*4 + r;
                vals[r] = acc[ms][ct][r] + bias[c];
                o4[r] = (short)f2bf(vals[r]);
            }
            *(s4v*)(outT + ((long long)b*HW + p)*128 + w*32 + ms*16 + q*4) = o4;
            if (outC){
                #pragma unroll
                for (int r = 0; r < 4; r++){
                    int c = w*32 + ms*16 + q*4 + r;
                    outC[((long long)b*128 + c)*HW + p] = (unsigned short)o4[r];
                }
            }
            if (outF){
                #pragma unroll
                for (int r = 0; r < 4; r++){
                    int c = w*32 + ms*16 + q*4 + r;
                    outF[((long long)b*128 + c)*HW + p] = vals[r];
                }
            }
        }
    }
}

// ---------------- pooled branch fused with broadcast into catT cols 1024..1279 ----------------
__global__ __launch_bounds__(256)
void k_poolbcast(const float* __restrict__ gp, const float* __restrict__ w,
                 const float* __restrict__ g, const float* __restrict__ bta,
                 unsigned short* __restrict__ catT){
    int b = blockIdx.y, p0 = blockIdx.x*128;
    int t = threadIdx.x;
    __shared__ float z_s[256];
    __shared__ unsigned short bp_s[256];
    __shared__ float stat[2];
    float z = 0.f;
    for (int c = 0; c < 256; c++) z += gp[b*256 + c] * w[t*256 + c];
    z_s[t] = z;
    __syncthreads();
    if (t == 0){
        float s = 0.f, s2 = 0.f;
        for (int c = 0; c < 256; c++){ s += z_s[c]; s2 += z_s[c]*z_s[c]; }
        float mean = s / 256.f, var = s2 / 256.f - mean*mean;
        stat[0] = mean; stat[1] = rsqrtf(var + 1e-6f);
    }
    __syncthreads();
    float h = g[t] * ((z - stat[0]) * stat[1]) + bta[t];
    bp_s[t] = f2bf(gelu_f(h));
    __syncthreads();
    for (int it = 0; it < 16; it++){
        int i = it*256 + t;
        int pl = i >> 5, cj = (i & 31) * 8;
        s8v v8;
        #pragma unroll
        for (int k2 = 0; k2 < 8; k2++) v8[k2] = (short)bp_s[cj + k2];
        *(s8v*)(catT + ((long long)b*HW + p0 + pl)*1280 + 1024 + cj) = v8;
    }
}

// ---------------- attention pass 1 (split-j, 128 k-rows/block, no-max softmax) ----------------
__global__ __launch_bounds__(256)
void k_attn_stats3(const unsigned short* __restrict__ QT,
                   const unsigned short* __restrict__ PT,
                   float* __restrict__ lpart){
    int b = blockIdx.z, jc = blockIdx.y, k0 = blockIdx.x * 128;
    const unsigned short* QTb = QT + (long long)b * HW * CO;
    const unsigned short* PTb = PT + (long long)b * HW * CO;
    __shared__ unsigned short Ps[2][64][132];
    int t = threadIdx.x;
    int w = t >> 6, lane = t & 63, m = lane & 15, q = lane >> 4;
    s8v a[2][4];
    #pragma unroll
    for (int kh = 0; kh < 2; kh++)
        #pragma unroll
        for (int ks = 0; ks < 4; ks++)
            a[kh][ks] = *(const s8v*)(QTb + (long long)(k0 + kh*64 + w*16 + m) * CO + q*8 + ks*32);
    float rl[2][4];
    #pragma unroll
    for (int kh = 0; kh < 2; kh++)
        #pragma unroll
        for (int r = 0; r < 4; r++) rl[kh][r] = 0.f;
    const float scale = 0.015625f;           // 1/sqrt(4096)
    int jbase = jc * 1024;
    int sr = t >> 2, sch = t & 3;
    uint4 pf[4];
    {   const uint4* src = (const uint4*)(PTb + (long long)(jbase + sr) * CO + sch * 32);
        #pragma unroll
        for (int i = 0; i < 4; i++) pf[i] = src[i];
    }
    for (int jt = 0; jt < 16; jt++){
        int cur = jt & 1;
        {   uint4* dst = (uint4*)&Ps[cur][sr][sch * 32];
            #pragma unroll
            for (int i = 0; i < 4; i++) dst[i] = pf[i];
        }
        __syncthreads();
        if (jt < 15){
            const uint4* src = (const uint4*)(PTb + (long long)(jbase + (jt+1)*64 + sr) * CO + sch * 32);
            #pragma unroll
            for (int i = 0; i < 4; i++) pf[i] = src[i];
        }
        #pragma unroll
        for (int kh = 0; kh < 2; kh++){
            float sv[4][4];
            #pragma unroll
            for (int ct = 0; ct < 4; ct++){
                f4v acc = {0.f,0.f,0.f,0.f};
                #pragma unroll
                for (int ks = 0; ks < 4; ks++){
                    s8v bv = *(const s8v*)&Ps[cur][ct*16 + m][q*8 + ks*32];
                    acc = __builtin_amdgcn_mfma_f32_16x16x32_bf16(a[kh][ks], bv, acc, 0, 0, 0);
                }
                #pragma unroll
                for (int r = 0; r < 4; r++) sv[ct][r] = acc[r] * scale;
            }
            #pragma unroll
            for (int r = 0; r < 4; r++){
                float se = __expf(sv[0][r]) + __expf(sv[1][r])
                         + __expf(sv[2][r]) + __expf(sv[3][r]);
                #pragma unroll
                for (int msk = 1; msk < 16; msk <<= 1) se += __shfl_xor(se, msk);
                rl[kh][r] += se;
            }
        }
    }
    if (m == 0){
        #pragma unroll
        for (int kh = 0; kh < 2; kh++)
            #pragma unroll
            for (int r = 0; r < 4; r++){
                int k = k0 + kh*64 + w*16 + q*4 + r;
                lpart[(long long)jc * (NB*HW) + (long long)b*HW + k] = rl[kh][r];
            }
    }
}

// ---------------- combine partial softmax sums: ilrow = 1/sum ----------------
__global__ void k_attn_comb(const float* __restrict__ lpart, float* __restrict__ ilrow){
    int i = blockIdx.x*256 + threadIdx.x;
    float l = lpart[i] + lpart[i+16384] + lpart[i+32768] + lpart[i+49152];
    ilrow[i] = 1.f / l;
}

// ---------------- attention pass 2 (split-k): R4 structure, no-max E ----------------
__global__ __launch_bounds__(256)
void k_attn_apply2(const unsigned short* __restrict__ QT,
                   const unsigned short* __restrict__ PT,
                   const unsigned short* __restrict__ Pb,
                   const float* __restrict__ ilrow,
                   float* __restrict__ Lp){
    int b = blockIdx.z, kc = blockIdx.y, j0 = blockIdx.x * 64;
    const unsigned short* QTb = QT + (long long)b * HW * CO;
    const unsigned short* PTb = PT + (long long)b * HW * CO;
    const unsigned short* Pbb = Pb + (long long)b * CO * HW;
    const float* lb = ilrow + (long long)b * HW;
    __shared__ unsigned short Qks[64][136];  // also Pjs during init (aliased)
    __shared__ unsigned short Pcs[128][72];
    __shared__ unsigned short Et[64][72];
    int t = threadIdx.x;
    int w = t >> 6, lane = t & 63, m = lane & 15, q = lane >> 4;
    {   // stage PT j-tile into Qks slot, read bj frags to registers
        int r = t >> 2, ch = t & 3;
        const uint4* src = (const uint4*)(PTb + (long long)(j0 + r) * CO + ch * 32);
        uint4* dst = (uint4*)&Qks[r][ch * 32];
        #pragma unroll
        for (int i = 0; i < 4; i++) dst[i] = src[i];
    }
    __syncthreads();
    s8v bj[4][4];
    #pragma unroll
    for (int ct = 0; ct < 4; ct++)
        #pragma unroll
        for (int ks = 0; ks < 4; ks++)
            bj[ct][ks] = *(const s8v*)&Qks[ct*16 + m][q*8 + ks*32];
    f4v accL[2][4];
    #pragma unroll
    for (int mt = 0; mt < 2; mt++)
        #pragma unroll
        for (int ct = 0; ct < 4; ct++){ f4v z = {0.f,0.f,0.f,0.f}; accL[mt][ct] = z; }
    const float scale = 0.015625f;
    int kbase = kc * 1024;
    for (int kt = 0; kt < 16; kt++){
        int k0 = kbase + kt*64;
        __syncthreads();
        {
            int r = t >> 2, ch = t & 3;
            const uint4* src = (const uint4*)(QTb + (long long)(k0 + r) * CO + ch * 32);
            uint4* dst = (uint4*)&Qks[r][ch * 32];
            #pragma unroll
            for (int i = 0; i < 4; i++) dst[i] = src[i];
        }
        {
            int c = t >> 1, hf = t & 1;
            const uint4* src = (const uint4*)(Pbb + (long long)c * HW + k0 + hf * 32);
            uint4* dst = (uint4*)&Pcs[c][hf * 32];
            #pragma unroll
            for (int i = 0; i < 4; i++) dst[i] = src[i];
        }
        __syncthreads();
        s8v aS[4];
        #pragma unroll
        for (int ks = 0; ks < 4; ks++) aS[ks] = *(const s8v*)&Qks[w*16 + m][q*8 + ks*32];
        float il[4];
        #pragma unroll
        for (int r = 0; r < 4; r++) il[r] = lb[k0 + w*16 + q*4 + r];
        #pragma unroll
        for (int ct = 0; ct < 4; ct++){
            f4v s = {0.f,0.f,0.f,0.f};
            #pragma unroll
            for (int ks = 0; ks < 4; ks++)
                s = __builtin_amdgcn_mfma_f32_16x16x32_bf16(aS[ks], bj[ct][ks], s, 0, 0, 0);
            s4v e4;
            #pragma unroll
            for (int r = 0; r < 4; r++)
                e4[r] = (short)f2bf(__expf(s[r]*scale) * il[r]);
            *(s4v*)&Et[ct*16 + m][w*16 + q*4] = e4;
        }
        __syncthreads();
        s8v aP[2][2];
        #pragma unroll
        for (int mt = 0; mt < 2; mt++)
            #pragma unroll
            for (int ks2 = 0; ks2 < 2; ks2++)
                aP[mt][ks2] = *(const s8v*)&Pcs[w*32 + mt*16 + m][q*8 + ks2*32];
        #pragma unroll
        for (int ct = 0; ct < 4; ct++){
            s8v bE0 = *(const s8v*)&Et[ct*16 + m][q*8];
            s8v bE1 = *(const s8v*)&Et[ct*16 + m][q*8 + 32];
            #pragma unroll
            for (int mt = 0; mt < 2; mt++){
                accL[mt][ct] = __builtin_amdgcn_mfma_f32_16x16x32_bf16(aP[mt][0], bE0, accL[mt][ct], 0, 0, 0);
                accL[mt][ct] = __builtin_amdgcn_mfma_f32_16x16x32_bf16(aP[mt][1], bE1, accL[mt][ct], 0, 0, 0);
            }
        }
    }
    float* Lpb = Lp + ((long long)(kc*NB + b) * CO) * HW;
    #pragma unroll
    for (int mt = 0; mt < 2; mt++)
        #pragma unroll
        for (int ct = 0; ct < 4; ct++)
            #pragma unroll
            for (int r = 0; r < 4; r++){
                int c = w*32 + mt*16 + q*4 + r;
                Lpb[(long long)c*HW + j0 + ct*16 + m] = accL[mt][ct][r];
            }
}

// ---------------- fused: O = xa + sum(Lp) -> bf16 B-tile -> conv2 -> out f32 ----------------
__global__ __launch_bounds__(256)
void k_outfused(const unsigned short* __restrict__ A,    // w_c2 [256][128] bf16
                const float* __restrict__ Lp, const float* __restrict__ xa,
                const float* __restrict__ bias, float* __restrict__ out){
    int b = blockIdx.y, j0 = blockIdx.x*32;
    __shared__ unsigned short Bs[32][136];
    __shared__ __align__(16) char pool[256*68*2];   // phase1: Bsf[128][33] f32; phase2: As[256][68] bf16
    int t = threadIdx.x;
    // phase 1: O tile f32 = xa + 4 partials (coalesced c-rows)
    {
        float* Bsf = (float*)pool;
        int c = t>>1, jh = t&1;
        long long base = ((long long)b*CO + c)*HW + j0 + jh*16;
        const long long csz = (long long)NB*CO*HW;
        float v[16];
        #pragma unroll
        for (int r = 0; r < 16; r++) v[r] = xa[base + r];
        #pragma unroll
        for (int pidx = 0; pidx < 4; pidx++){
            const float* src = Lp + pidx*csz + base;
            #pragma unroll
            for (int r = 0; r < 16; r++) v[r] += src[r];
        }
        #pragma unroll
        for (int r = 0; r < 16; r++) Bsf[c*33 + jh*16 + r] = v[r];
    }
    __syncthreads();
    // transpose to bf16 B-tile [j][c]
    {
        const float* Bsf = (const float*)pool;
        int j = t>>3, cs = t&7;
        #pragma unroll
        for (int r = 0; r < 16; r++){
            int c = cs*16 + r;
            Bs[j][c] = f2bf(Bsf[c*33 + j]);
        }
    }
    __syncthreads();
    // phase 2: GEMM M=256 x N=32 x K=128
    unsigned short (*As)[68] = (unsigned short(*)[68])pool;
    int w = t>>6, lane = t&63, m = lane&15, q = lane>>4;
    f4v acc[4][2];
    #pragma unroll
    for (int ms = 0; ms < 4; ms++)
        #pragma unroll
        for (int ct = 0; ct < 2; ct++){ f4v z = {0.f,0.f,0.f,0.f}; acc[ms][ct] = z; }
    for (int k0 = 0; k0 < 128; k0 += 64){
        __syncthreads();
        {   const uint4* src = (const uint4*)(A + (long long)t*128 + k0);
            uint4* dst = (uint4*)&As[t][0];
            #pragma unroll
            for (int i = 0; i < 8; i++) dst[i] = src[i];
        }
        __syncthreads();
        #pragma unroll
        for (int ks = 0; ks < 2; ks++){
            s8v bfr[2];
            #pragma unroll
            for (int ct = 0; ct < 2; ct++) bfr[ct] = *(const s8v*)&Bs[ct*16+m][k0 + ks*32 + q*8];
            #pragma unroll
            for (int ms = 0; ms < 4; ms++){
                s8v afr = *(const s8v*)&As[w*64 + ms*16 + m][q*8 + ks*32];
                #pragma unroll
                for (int ct = 0; ct < 2; ct++)
                    acc[ms][ct] = __builtin_amdgcn_mfma_f32_16x16x32_bf16(afr, bfr[ct], acc[ms][ct], 0,0,0);
            }
        }
    }
    #pragma unroll
    for (int ct = 0; ct < 2; ct++){
        int p = j0 + ct*16 + m;
        #pragma unroll
        for (int ms = 0; ms < 4; ms++)
            #pragma unroll
            for (int r = 0; r < 4; r++){
                int c = w*64 + ms*16 + q*4 + r;
                out[((long long)b*256 + c)*HW + p] = acc[ms][ct][r] + bias[c];
            }
    }
}

extern "C" void kernel_launch(void* const* d_in, const int* in_sizes, int n_in,
                              void* d_out, int out_size, void* d_ws, size_t ws_size,
                              hipStream_t stream) {
    const float* x       = (const float*)d_in[0];
    const float* conv1_w = (const float*)d_in[1];
    const float* conv1_b = (const float*)d_in[2];
    const float* conv2_w = (const float*)d_in[3];
    const float* conv2_b = (const float*)d_in[4];
    const float* cw_w1   = (const float*)d_in[5];
    const float* cw_b1   = (const float*)d_in[6];
    const float* cw_g    = (const float*)d_in[7];
    const float* cw_bt   = (const float*)d_in[8];
    const float* cw_w2   = (const float*)d_in[9];
    const float* cw_b2   = (const float*)d_in[10];
    const float* a0_w    = (const float*)d_in[11];
    const float* a0_g    = (const float*)d_in[12];
    const float* a0_b    = (const float*)d_in[13];
    const float* a1_w    = (const float*)d_in[14];
    const float* a1_g    = (const float*)d_in[15];
    const float* a1_b    = (const float*)d_in[16];
    const float* a2_w    = (const float*)d_in[17];
    const float* a2_g    = (const float*)d_in[18];
    const float* a2_b    = (const float*)d_in[19];
    const float* a3_w    = (const float*)d_in[20];
    const float* a3_g    = (const float*)d_in[21];
    const float* a3_b    = (const float*)d_in[22];
    const float* ap_w    = (const float*)d_in[23];
    const float* ap_g    = (const float*)d_in[24];
    const float* ap_b    = (const float*)d_in[25];
    const float* pj_w    = (const float*)d_in[26];
    const float* pj_g    = (const float*)d_in[27];
    const float* pj_b    = (const float*)d_in[28];
    float* out = (float*)d_out;

    // ---- workspace layout ----
    float* ws    = (float*)d_ws;
    float* avg   = ws;                  // 1024
    float* mx    = ws + 1024;           // 1024
    float* sv    = ws + 2048;           // 1024
    float* gp    = ws + 3072;           // 1024
    float* ilrow = ws + 21504;          // 16384
    float* xa    = ws + 37888;          // 2,097,152
    float* lpart = xa + 2097152;        // 65536
    unsigned short* sb = (unsigned short*)(ws + 4232192);
    unsigned short* xT    = sb;                    // 4,194,304
    unsigned short* xcT   = sb + 4194304;          // 4,194,304
    unsigned short* catT  = sb + 8388608;          // 20,971,520
    unsigned short* projT = sb + 29360128;         // 4,194,304
    unsigned short* P_bf  = sb + 33554432;         // 2,097,152
    unsigned short* PT_bf = sb + 35651584;         // 2,097,152
    unsigned short* QT_bf = sb + 37748736;         // 2,097,152
    unsigned short* w_c1  = sb + 41943040;         // 32768
    unsigned short* w_a0  = sb + 41975808;         // 65536
    unsigned short* w_pj  = sb + 42041344;         // 327680
    unsigned short* w_c2  = sb + 42369024;         // 32768
    unsigned short* w_d3  = sb + 42401792;         // 589824
    unsigned short* w_d6  = sb + 42991616;         // 589824
    unsigned short* w_d9  = sb + 43581440;         // 589824
    float* Lp = (float*)catT;           // alias: catT dead after proj (33.5MB in 42MB region)

    // ---- stats + channel weighting ----
    k_rowstats<<<dim3(NB*CI), 256, 0, stream>>>(x, avg, mx);
    k_cw<<<dim3(NB), 256, 0, stream>>>(avg, mx, cw_w1, cw_b1, cw_g, cw_bt, cw_w2, cw_b2, sv, gp);

    // ---- all weight casts (one launch) ----
    k_allcast<<<dim3(8704), 256, 0, stream>>>(conv1_w, a0_w, pj_w, conv2_w, a1_w, a2_w, a3_w,
                                              w_c1, w_a0, w_pj, w_c2, w_d3, w_d6, w_d9);

    // ---- x -> xT bf16 and xcT ----
    k_xT<<<dim3(64, 4, NB), 256, 0, stream>>>(x, sv, xT, xcT);

    // ---- x1 = conv1(x)+b -> P_bf/PT_bf ----
    k_conv1m<<<dim3(128, NB), 256, 0, stream>>>(w_c1, xT, conv1_b, PT_bf, P_bf, nullptr);

    // ---- ASPP branches (fused conv+LN+GELU -> catT bf16) ----
    k_branch1<<<dim3(128, NB), 512, 0, stream>>>(w_a0, 256, xcT, a0_g, a0_b, catT, 1280, 0);
    k_branch3<<<dim3(128, NB), 512, 0, stream>>>(w_d3, xcT, 3, a1_g, a1_b, catT, 256);
    k_branch3<<<dim3(128, NB), 512, 0, stream>>>(w_d6, xcT, 6, a2_g, a2_b, catT, 512);
    k_branch3<<<dim3(128, NB), 512, 0, stream>>>(w_d9, xcT, 9, a3_g, a3_b, catT, 768);
    k_poolbcast<<<dim3(32, NB), 256, 0, stream>>>(gp, ap_w, ap_g, ap_b, catT);

    // ---- proj = GELU(LN(conv1x1(cat))) -> projT bf16 ----
    k_branch1<<<dim3(128, NB), 512, 0, stream>>>(w_pj, 1280, catT, pj_g, pj_b, projT, 256, 0);

    // ---- xa = conv1(proj)+b -> xa f32 + QT_bf ----
    k_conv1m<<<dim3(128, NB), 256, 0, stream>>>(w_c1, projT, conv1_b, QT_bf, nullptr, xa);

    // ---- attention (no-max softmax: stats accumulate sum-exp only) ----
    k_attn_stats3<<<dim3(32, 4, NB), 256, 0, stream>>>(QT_bf, PT_bf, lpart);
    k_attn_comb<<<dim3(64), 256, 0, stream>>>(lpart, ilrow);
    k_attn_apply2<<<dim3(64, 4, NB), 256, 0, stream>>>(QT_bf, PT_bf, P_bf, ilrow, Lp);

    // ---- out = conv2(xa + sum Lp) + b (fused) ----
    k_outfused<<<dim3(128, NB), 256, 0, stream>>>(w_c2, Lp, xa, conv2_b, out);

    (void)in_sizes; (void)n_in; (void)out_size; (void)ws_size;
}

// Round 10
// 500.573 us; speedup vs baseline: 1.2566x; 1.0721x over previous
//
#include <hip/hip_runtime.h>
#include <hip/hip_bf16.h>
#include <math.h>

// Problem constants (B=4, Cin=256, Cout=128, H=W=64)
#define NB 4
#define CI 256
#define CO 128
#define HW 4096

typedef __attribute__((ext_vector_type(8))) short s8v;   // 8 bf16 = 4 VGPRs (MFMA A/B frag)
typedef __attribute__((ext_vector_type(4))) short s4v;
typedef __attribute__((ext_vector_type(4))) float f4v;   // MFMA C/D frag

__device__ __forceinline__ unsigned short f2bf(float f){
    __hip_bfloat16 h = __float2bfloat16(f);   // RNE
    return *reinterpret_cast<unsigned short*>(&h);
}

// A&S 7.1.26 erf (max abs err 1.5e-7)
__device__ __forceinline__ float gelu_f(float x){
    float z  = x * 0.70710678118654752f;
    float az = fabsf(z);
    float tt = 1.f / (1.f + 0.3275911f * az);
    float poly = tt*(0.254829592f + tt*(-0.284496736f + tt*(1.421413741f +
                 tt*(-1.453152027f + tt*1.061405429f))));
    float erfv = 1.f - poly * __expf(-az*az);
    erfv = (z < 0.f) ? -erfv : erfv;
    return 0.5f * x * (1.f + erfv);
}

// ---------------- fused: per-channel avg/max (blocks 0..1023) + ALL weight casts ----------------
__global__ void k_pre(const float* __restrict__ x, float* __restrict__ avg, float* __restrict__ mx,
                      const float* __restrict__ c1, const float* __restrict__ a0,
                      const float* __restrict__ pj, const float* __restrict__ c2,
                      const float* __restrict__ d3, const float* __restrict__ d6,
                      const float* __restrict__ d9,
                      unsigned short* __restrict__ w_c1, unsigned short* __restrict__ w_a0,
                      unsigned short* __restrict__ w_pj, unsigned short* __restrict__ w_c2,
                      unsigned short* __restrict__ w_d3, unsigned short* __restrict__ w_d6,
                      unsigned short* __restrict__ w_d9){
    int blk = blockIdx.x;
    int t = threadIdx.x;
    if (blk < 1024){
        const float* p = x + (long long)blk * HW;
        float s = 0.f, m = -1e30f;
        for (int i = t; i < HW; i += 256){ float v = p[i]; s += v; m = fmaxf(m, v); }
        __shared__ float ss[256], sm[256];
        ss[t] = s; sm[t] = m; __syncthreads();
        for (int o = 128; o > 0; o >>= 1){
            if (t < o){ ss[t] += ss[t+o]; sm[t] = fmaxf(sm[t], sm[t+o]); }
            __syncthreads();
        }
        if (t == 0){ avg[blk] = ss[0] / (float)HW; mx[blk] = sm[0]; }
        return;
    }
    int i = (blk - 1024)*256 + t;
    if (i < 458752){
        if (i < 32768)        w_c1[i]        = f2bf(c1[i]);
        else if (i < 98304)   w_a0[i-32768]  = f2bf(a0[i-32768]);
        else if (i < 425984)  w_pj[i-98304]  = f2bf(pj[i-98304]);
        else                  w_c2[i-425984] = f2bf(c2[i-425984]);
    } else {
        int j = i - 458752;
        int which = j / 589824;
        int l = j - which*589824;
        int tap = l >> 16, rem = l & 65535, o = rem >> 8, ci = rem & 255;
        const float* src = (which==0) ? d3 : ((which==1) ? d6 : d9);
        unsigned short* dst = (which==0) ? w_d3 : ((which==1) ? w_d6 : w_d9);
        dst[l] = f2bf(src[o*2304 + ci*9 + tap]);
    }
}

// ---------------- ChannelWeighting; also gp = avg*(1+s) ----------------
__global__ void k_cw(const float* __restrict__ avg, const float* __restrict__ mx,
                     const float* __restrict__ w1, const float* __restrict__ b1,
                     const float* __restrict__ lng, const float* __restrict__ lnb,
                     const float* __restrict__ w2, const float* __restrict__ b2,
                     float* __restrict__ sv, float* __restrict__ gp){
    int b = blockIdx.x, t = threadIdx.x;
    __shared__ float o_s[256];
    __shared__ float h_s[128];
    __shared__ float stat[2];
    float a = avg[b*256 + t];
    o_s[t] = fabsf(a - mx[b*256 + t]) * a;
    __syncthreads();
    if (t < 128){
        float h = b1[t];
        for (int i = 0; i < 256; i++) h += o_s[i] * w1[t*256 + i];
        h_s[t] = h;
    }
    __syncthreads();
    if (t == 0){
        float s = 0.f, s2 = 0.f;
        for (int j = 0; j < 128; j++){ s += h_s[j]; s2 += h_s[j]*h_s[j]; }
        float mean = s / 128.f;
        float var  = s2 / 128.f - mean*mean;
        stat[0] = mean; stat[1] = rsqrtf(var + 1e-5f);
    }
    __syncthreads();
    if (t < 128) h_s[t] = lng[t] * ((h_s[t] - stat[0]) * stat[1]) + lnb[t];
    __syncthreads();
    float z = b2[t];
    for (int j = 0; j < 128; j++) z += h_s[j] * w2[t*128 + j];
    float sig = 1.f / (1.f + __expf(-z));
    sv[b*256 + t] = sig;
    gp[b*256 + t] = a * (1.f + sig);
}

// ---------------- x -> xT bf16 [b][HW][256] and xcT = bf16(x*(1+s)) ----------------
__global__ void k_xT(const float* __restrict__ x, const float* __restrict__ sv,
                     unsigned short* __restrict__ xT, unsigned short* __restrict__ xcT){
    int b = blockIdx.z, c0 = blockIdx.y*64, h0 = blockIdx.x*64;
    __shared__ unsigned short T1[64][66], T2[64][66];
    int t = threadIdx.x;
    int hl = t & 63, cs = t >> 6;
    #pragma unroll
    for (int r = 0; r < 16; r++){
        int c = cs*16 + r;
        float v = x[((long long)b*256 + c0 + c)*HW + h0 + hl];
        float sc = 1.f + sv[b*256 + c0 + c];
        T1[c][hl] = f2bf(v);
        T2[c][hl] = f2bf(v*sc);
    }
    __syncthreads();
    int cl = t & 63, hs = t >> 6;
    #pragma unroll
    for (int r = 0; r < 16; r++){
        int h = hs*16 + r;
        long long o = ((long long)b*HW + h0 + h)*256 + c0 + cl;
        xT[o]  = T1[cl][h];
        xcT[o] = T2[cl][h];
    }
}

// ============ 8-wave epilogue, N=32: LN(256ch)+GELU -> transposed bf16 ============
__device__ __forceinline__ void ln_epi32(f4v acc[2][2],
        int b, int n0, int w, int lane, int m, int q, int t,
        const float* Gs, const float* Bts,
        float (*Psum)[32], float (*Psq)[32], float* Mn, float* Iv,
        unsigned short* __restrict__ outT, int outPitch, int colOff){
    float ls[2], ls2[2];
    #pragma unroll
    for (int ct = 0; ct < 2; ct++){
        float s = 0.f, s2 = 0.f;
        #pragma unroll
        for (int ms = 0; ms < 2; ms++)
            #pragma unroll
            for (int r = 0; r < 4; r++){ float v = acc[ms][ct][r]; s += v; s2 += v*v; }
        ls[ct] = s; ls2[ct] = s2;
    }
    #pragma unroll
    for (int ct = 0; ct < 2; ct++){
        ls[ct]  += __shfl_xor(ls[ct], 16);  ls[ct]  += __shfl_xor(ls[ct], 32);
        ls2[ct] += __shfl_xor(ls2[ct], 16); ls2[ct] += __shfl_xor(ls2[ct], 32);
    }
    if (lane < 16){
        #pragma unroll
        for (int ct = 0; ct < 2; ct++){ Psum[w][ct*16+lane] = ls[ct]; Psq[w][ct*16+lane] = ls2[ct]; }
    }
    __syncthreads();
    if (t < 32){
        float s = 0.f, s2 = 0.f;
        #pragma unroll
        for (int ww = 0; ww < 8; ww++){ s += Psum[ww][t]; s2 += Psq[ww][t]; }
        float mean = s * (1.f/256.f);
        Mn[t] = mean;
        Iv[t] = rsqrtf(s2*(1.f/256.f) - mean*mean + 1e-6f);
    }
    __syncthreads();
    #pragma unroll
    for (int ct = 0; ct < 2; ct++){
        int p = ct*16 + m;
        float mean = Mn[p], inv = Iv[p];
        long long rowb = ((long long)b*HW + n0 + p)*outPitch + colOff;
        #pragma unroll
        for (int ms = 0; ms < 2; ms++){
            s4v o4;
            #pragma unroll
            for (int r = 0; r < 4; r++){
                int c = w*32 + ms*16 + q*4 + r;
                float h = Gs[c]*((acc[ms][ct][r] - mean)*inv) + Bts[c];
                o4[r] = (short)f2bf(gelu_f(h));
            }
            *(s4v*)(outT + rowb + w*32 + ms*16 + q*4) = o4;
        }
    }
}

// ---------------- unified ASPP: y=0 a0 1x1 | y=1..3 dilated 3x3 | y=4 pool+bcast ----------------
__global__ __launch_bounds__(512)
void k_aspp(const unsigned short* __restrict__ w_a0, const unsigned short* __restrict__ w_d3,
            const unsigned short* __restrict__ w_d6, const unsigned short* __restrict__ w_d9,
            const unsigned short* __restrict__ BT,
            const float* __restrict__ a0_g, const float* __restrict__ a0_b,
            const float* __restrict__ a1_g, const float* __restrict__ a1_b,
            const float* __restrict__ a2_g, const float* __restrict__ a2_b,
            const float* __restrict__ a3_g, const float* __restrict__ a3_b,
            const float* __restrict__ gp, const float* __restrict__ ap_w,
            const float* __restrict__ ap_g, const float* __restrict__ ap_b,
            unsigned short* __restrict__ catT){
    int br = blockIdx.y, b = blockIdx.z;
    int t = threadIdx.x;
    __shared__ unsigned short As[256][72];
    __shared__ unsigned short Bs[32][72];
    __shared__ float Psum[8][32], Psq[8][32], Mn[32], Iv[32];
    __shared__ float Gs[256], Bts[256];
    if (br == 4){
        // ---- pool + broadcast (x<32 active) ----
        if (blockIdx.x >= 32) return;
        int p0 = blockIdx.x*128;
        float* z_s = (float*)&As[0][0];                 // 256 f32, aliased scratch
        unsigned short* bp_s = (unsigned short*)&As[32][0]; // 256 bf16
        float* stat = (float*)&As[64][0];
        if (t < 256){
            float z = 0.f;
            for (int c = 0; c < 256; c++) z += gp[b*256 + c] * ap_w[t*256 + c];
            z_s[t] = z;
        }
        __syncthreads();
        if (t == 0){
            float s = 0.f, s2 = 0.f;
            for (int c = 0; c < 256; c++){ s += z_s[c]; s2 += z_s[c]*z_s[c]; }
            float mean = s / 256.f, var = s2 / 256.f - mean*mean;
            stat[0] = mean; stat[1] = rsqrtf(var + 1e-6f);
        }
        __syncthreads();
        if (t < 256){
            float h = ap_g[t] * ((z_s[t] - stat[0]) * stat[1]) + ap_b[t];
            bp_s[t] = f2bf(gelu_f(h));
        }
        __syncthreads();
        for (int it = 0; it < 8; it++){
            int i = it*512 + t;
            int pl = i >> 5, cj = (i & 31) * 8;
            s8v v8;
            #pragma unroll
            for (int k2 = 0; k2 < 8; k2++) v8[k2] = (short)bp_s[cj + k2];
            *(s8v*)(catT + ((long long)b*HW + p0 + pl)*1280 + 1024 + cj) = v8;
        }
        return;
    }
    // ---- conv branches ----
    int n0 = blockIdx.x*32;
    const unsigned short* BTb = BT + (long long)b*HW*256;
    const unsigned short* A  = (br==0) ? w_a0 : (br==1) ? w_d3 : (br==2) ? w_d6 : w_d9;
    const float* g   = (br==0) ? a0_g : (br==1) ? a1_g : (br==2) ? a2_g : a3_g;
    const float* bta = (br==0) ? a0_b : (br==1) ? a1_b : (br==2) ? a2_b : a3_b;
    int w = t>>6, lane = t&63, m = lane&15, q = lane>>4;
    if (t < 256){ Gs[t] = g[t]; Bts[t] = bta[t]; }
    f4v acc[2][2];
    #pragma unroll
    for (int ms = 0; ms < 2; ms++)
        #pragma unroll
        for (int ct = 0; ct < 2; ct++){ f4v z = {0.f,0.f,0.f,0.f}; acc[ms][ct] = z; }
    if (br == 0){
        for (int k0 = 0; k0 < 256; k0 += 64){
            __syncthreads();
            {   int r = t>>1, half = t&1;
                const uint4* src = (const uint4*)(A + (long long)r*256 + k0 + half*32);
                uint4* dst = (uint4*)&As[r][half*32];
                dst[0]=src[0]; dst[1]=src[1]; dst[2]=src[2]; dst[3]=src[3];
            }
            {   int n = t>>4, ch = t&15;
                *(uint2*)&Bs[n][ch*4] = *(const uint2*)(BTb + (long long)(n0+n)*256 + k0 + ch*4);
            }
            __syncthreads();
            #pragma unroll
            for (int ks = 0; ks < 2; ks++){
                s8v bfr[2];
                #pragma unroll
                for (int ct = 0; ct < 2; ct++) bfr[ct] = *(const s8v*)&Bs[ct*16+m][q*8+ks*32];
                #pragma unroll
                for (int ms = 0; ms < 2; ms++){
                    s8v afr = *(const s8v*)&As[w*32 + ms*16 + m][q*8+ks*32];
                    #pragma unroll
                    for (int ct = 0; ct < 2; ct++)
                        acc[ms][ct] = __builtin_amdgcn_mfma_f32_16x16x32_bf16(afr, bfr[ct], acc[ms][ct], 0,0,0);
                }
            }
        }
    } else {
        int d = (br==1) ? 3 : (br==2) ? 6 : 9;
        int y = n0 >> 6, x0 = n0 & 63;
        for (int tap = 0; tap < 9; tap++){
            int dy = tap/3 - 1, dx = tap%3 - 1;
            int ys = y + dy*d;
            bool yok = (unsigned)ys < 64u;
            const unsigned short* wtap = A + (long long)tap*65536;
            for (int kc = 0; kc < 4; kc++){
                int ci0 = kc*64;
                __syncthreads();
                {   int r = t>>1, half = t&1;
                    const uint4* src = (const uint4*)(wtap + (long long)r*256 + ci0 + half*32);
                    uint4* dst = (uint4*)&As[r][half*32];
                    dst[0]=src[0]; dst[1]=src[1]; dst[2]=src[2]; dst[3]=src[3];
                }
                {   int n = t>>4, ch = t&15;
                    int xs = x0 + n + dx*d;
                    uint2 v = {0u,0u};
                    if (yok && (unsigned)xs < 64u)
                        v = *(const uint2*)(BTb + (long long)(ys*64+xs)*256 + ci0 + ch*4);
                    *(uint2*)&Bs[n][ch*4] = v;
                }
                __syncthreads();
                #pragma unroll
                for (int ks = 0; ks < 2; ks++){
                    s8v bfr[2];
                    #pragma unroll
                    for (int ct = 0; ct < 2; ct++) bfr[ct] = *(const s8v*)&Bs[ct*16+m][q*8+ks*32];
                    #pragma unroll
                    for (int ms = 0; ms < 2; ms++){
                        s8v afr = *(const s8v*)&As[w*32 + ms*16 + m][q*8+ks*32];
                        #pragma unroll
                        for (int ct = 0; ct < 2; ct++)
                            acc[ms][ct] = __builtin_amdgcn_mfma_f32_16x16x32_bf16(afr, bfr[ct], acc[ms][ct], 0,0,0);
                    }
                }
            }
        }
    }
    __syncthreads();
    ln_epi32(acc, b, n0, w, lane, m, q, t, Gs, Bts, Psum, Psq, Mn, Iv, catT, 1280, br*256);
}

// ---------------- fused 1x1-conv (MFMA) + LN + GELU, 512 thr (proj) ----------------
__global__ __launch_bounds__(512)
void k_branch1(const unsigned short* __restrict__ A, int K,
               const unsigned short* __restrict__ BT,
               const float* __restrict__ g, const float* __restrict__ beta,
               unsigned short* __restrict__ outT, int outPitch, int colOff){
    int b = blockIdx.y, n0 = blockIdx.x*32;
    const unsigned short* BTb = BT + (long long)b*HW*K;
    __shared__ unsigned short As[256][72];
    __shared__ unsigned short Bs[32][72];
    __shared__ float Psum[8][32], Psq[8][32], Mn[32], Iv[32];
    __shared__ float Gs[256], Bts[256];
    int t = threadIdx.x, w = t>>6, lane = t&63, m = lane&15, q = lane>>4;
    if (t < 256){ Gs[t] = g[t]; Bts[t] = beta[t]; }
    f4v acc[2][2];
    #pragma unroll
    for (int ms = 0; ms < 2; ms++)
        #pragma unroll
        for (int ct = 0; ct < 2; ct++){ f4v z = {0.f,0.f,0.f,0.f}; acc[ms][ct] = z; }
    for (int k0 = 0; k0 < K; k0 += 64){
        __syncthreads();
        {   int r = t>>1, half = t&1;
            const uint4* src = (const uint4*)(A + (long long)r*K + k0 + half*32);
            uint4* dst = (uint4*)&As[r][half*32];
            dst[0]=src[0]; dst[1]=src[1]; dst[2]=src[2]; dst[3]=src[3];
        }
        {   int n = t>>4, ch = t&15;
            *(uint2*)&Bs[n][ch*4] = *(const uint2*)(BTb + (long long)(n0+n)*K + k0 + ch*4);
        }
        __syncthreads();
        #pragma unroll
        for (int ks = 0; ks < 2; ks++){
            s8v bfr[2];
            #pragma unroll
            for (int ct = 0; ct < 2; ct++) bfr[ct] = *(const s8v*)&Bs[ct*16+m][q*8+ks*32];
            #pragma unroll
            for (int ms = 0; ms < 2; ms++){
                s8v afr = *(const s8v*)&As[w*32 + ms*16 + m][q*8+ks*32];
                #pragma unroll
                for (int ct = 0; ct < 2; ct++)
                    acc[ms][ct] = __builtin_amdgcn_mfma_f32_16x16x32_bf16(afr, bfr[ct], acc[ms][ct], 0,0,0);
            }
        }
    }
    __syncthreads();
    ln_epi32(acc, b, n0, w, lane, m, q, t, Gs, Bts, Psum, Psq, Mn, Iv, outT, outPitch, colOff);
}

// ---------------- conv1 (M=128) MFMA, 256 thr, N=32, Kstage=64 ----------------
__global__ __launch_bounds__(256)
void k_conv1m(const unsigned short* __restrict__ A,      // [128][256] bf16
              const unsigned short* __restrict__ BT,     // [b][HW][256] bf16
              const float* __restrict__ bias,
              unsigned short* __restrict__ outT,         // [b][HW][128] bf16
              unsigned short* __restrict__ outC,         // [b][128][HW] bf16 or null
              float* __restrict__ outF){                 // [b][128][HW] f32 or null
    int b = blockIdx.y, n0 = blockIdx.x*32;
    const unsigned short* BTb = BT + (long long)b*HW*256;
    __shared__ unsigned short As[128][72];
    __shared__ unsigned short Bs[32][72];
    int t = threadIdx.x, w = t>>6, lane = t&63, m = lane&15, q = lane>>4;
    f4v acc[2][2];
    #pragma unroll
    for (int ms = 0; ms < 2; ms++)
        #pragma unroll
        for (int ct = 0; ct < 2; ct++){ f4v z = {0.f,0.f,0.f,0.f}; acc[ms][ct] = z; }
    for (int k0 = 0; k0 < 256; k0 += 64){
        __syncthreads();
        {   int r = t>>1, half = t&1;
            const uint4* src = (const uint4*)(A + (long long)r*256 + k0 + half*32);
            uint4* dst = (uint4*)&As[r][half*32];
            dst[0]=src[0]; dst[1]=src[1]; dst[2]=src[2]; dst[3]=src[3];
        }
        {   int n = t>>3, ch = t&7;
            *(uint4*)&Bs[n][ch*8] = *(const uint4*)(BTb + (long long)(n0+n)*256 + k0 + ch*8);
        }
        __syncthreads();
        #pragma unroll
        for (int ks = 0; ks < 2; ks++){
            s8v bfr[2];
            #pragma unroll
            for (int ct = 0; ct < 2; ct++) bfr[ct] = *(const s8v*)&Bs[ct*16+m][q*8+ks*32];
            #pragma unroll
            for (int ms = 0; ms < 2; ms++){
                s8v afr = *(const s8v*)&As[w*32 + ms*16 + m][q*8+ks*32];
                #pragma unroll
                for (int ct = 0; ct < 2; ct++)
                    acc[ms][ct] = __builtin_amdgcn_mfma_f32_16x16x32_bf16(afr, bfr[ct], acc[ms][ct], 0,0,0);
            }
        }
    }
    #pragma unroll
    for (int ct = 0; ct < 2; ct++){
        int p = n0 + ct*16 + m;
        #pragma unroll
        for (int ms = 0; ms < 2; ms++){
            s4v o4;
            float vals[4];
            #pragma unroll
            for (int r = 0; r < 4; r++){
                int c = w*32 + ms*16 + q*4 + r;
                vals[r] = acc[ms][ct][r] + bias[c];
                o4[r] = (short)f2bf(vals[r]);
            }
            *(s4v*)(outT + ((long long)b*HW + p)*128 + w*32 + ms*16 + q*4) = o4;
            if (outC){
                #pragma unroll
                for (int r = 0; r < 4; r++){
                    int c = w*32 + ms*16 + q*4 + r;
                    outC[((long long)b*128 + c)*HW + p] = (unsigned short)o4[r];
                }
            }
            if (outF){
                #pragma unroll
                for (int r = 0; r < 4; r++){
                    int c = w*32 + ms*16 + q*4 + r;
                    outF[((long long)b*128 + c)*HW + p] = vals[r];
                }
            }
        }
    }
}

// ---------------- attention pass 1 (split-j, 128 k-rows/block, no-max softmax) ----------------
__global__ __launch_bounds__(256)
void k_attn_stats3(const unsigned short* __restrict__ QT,
                   const unsigned short* __restrict__ PT,
                   float* __restrict__ lpart){
    int b = blockIdx.z, jc = blockIdx.y, k0 = blockIdx.x * 128;
    const unsigned short* QTb = QT + (long long)b * HW * CO;
    const unsigned short* PTb = PT + (long long)b * HW * CO;
    __shared__ unsigned short Ps[2][64][132];
    int t = threadIdx.x;
    int w = t >> 6, lane = t & 63, m = lane & 15, q = lane >> 4;
    s8v a[2][4];
    #pragma unroll
    for (int kh = 0; kh < 2; kh++)
        #pragma unroll
        for (int ks = 0; ks < 4; ks++)
            a[kh][ks] = *(const s8v*)(QTb + (long long)(k0 + kh*64 + w*16 + m) * CO + q*8 + ks*32);
    float rl[2][4];
    #pragma unroll
    for (int kh = 0; kh < 2; kh++)
        #pragma unroll
        for (int r = 0; r < 4; r++) rl[kh][r] = 0.f;
    const float scale = 0.015625f;           // 1/sqrt(4096)
    int jbase = jc * 1024;
    int sr = t >> 2, sch = t & 3;
    uint4 pf[4];
    {   const uint4* src = (const uint4*)(PTb + (long long)(jbase + sr) * CO + sch * 32);
        #pragma unroll
        for (int i = 0; i < 4; i++) pf[i] = src[i];
    }
    for (int jt = 0; jt < 16; jt++){
        int cur = jt & 1;
        {   uint4* dst = (uint4*)&Ps[cur][sr][sch * 32];
            #pragma unroll
            for (int i = 0; i < 4; i++) dst[i] = pf[i];
        }
        __syncthreads();
        if (jt < 15){
            const uint4* src = (const uint4*)(PTb + (long long)(jbase + (jt+1)*64 + sr) * CO + sch * 32);
            #pragma unroll
            for (int i = 0; i < 4; i++) pf[i] = src[i];
        }
        #pragma unroll
        for (int kh = 0; kh < 2; kh++){
            float sv[4][4];
            #pragma unroll
            for (int ct = 0; ct < 4; ct++){
                f4v acc = {0.f,0.f,0.f,0.f};
                #pragma unroll
                for (int ks = 0; ks < 4; ks++){
                    s8v bv = *(const s8v*)&Ps[cur][ct*16 + m][q*8 + ks*32];
                    acc = __builtin_amdgcn_mfma_f32_16x16x32_bf16(a[kh][ks], bv, acc, 0, 0, 0);
                }
                #pragma unroll
                for (int r = 0; r < 4; r++) sv[ct][r] = acc[r] * scale;
            }
            #pragma unroll
            for (int r = 0; r < 4; r++){
                float se = __expf(sv[0][r]) + __expf(sv[1][r])
                         + __expf(sv[2][r]) + __expf(sv[3][r]);
                #pragma unroll
                for (int msk = 1; msk < 16; msk <<= 1) se += __shfl_xor(se, msk);
                rl[kh][r] += se;
            }
        }
    }
    if (m == 0){
        #pragma unroll
        for (int kh = 0; kh < 2; kh++)
            #pragma unroll
            for (int r = 0; r < 4; r++){
                int k = k0 + kh*64 + w*16 + q*4 + r;
                lpart[(long long)jc * (NB*HW) + (long long)b*HW + k] = rl[kh][r];
            }
    }
}

// ---------------- attention pass 2 (split-k): R4 structure, no-max E, fused comb ----------------
__global__ __launch_bounds__(256)
void k_attn_apply2(const unsigned short* __restrict__ QT,
                   const unsigned short* __restrict__ PT,
                   const unsigned short* __restrict__ Pb,
                   const float* __restrict__ lpart,
                   float* __restrict__ Lp){
    int b = blockIdx.z, kc = blockIdx.y, j0 = blockIdx.x * 64;
    const unsigned short* QTb = QT + (long long)b * HW * CO;
    const unsigned short* PTb = PT + (long long)b * HW * CO;
    const unsigned short* Pbb = Pb + (long long)b * CO * HW;
    __shared__ unsigned short Qks[64][136];  // also Pjs during init (aliased)
    __shared__ unsigned short Pcs[128][72];
    __shared__ unsigned short Et[64][72];
    __shared__ float Il[1024];
    int t = threadIdx.x;
    int w = t >> 6, lane = t & 63, m = lane & 15, q = lane >> 4;
    int kbase = kc * 1024;
    {   // fused stat combine (plain sum, no-max): Il for this block's k-range
        #pragma unroll
        for (int r = 0; r < 4; r++){
            int kl = t*4 + r;
            long long gi = (long long)b*HW + kbase + kl;
            float l = lpart[gi] + lpart[gi+16384] + lpart[gi+32768] + lpart[gi+49152];
            Il[kl] = 1.f / l;
        }
    }
    {   // stage PT j-tile into Qks slot, read bj frags to registers
        int r = t >> 2, ch = t & 3;
        const uint4* src = (const uint4*)(PTb + (long long)(j0 + r) * CO + ch * 32);
        uint4* dst = (uint4*)&Qks[r][ch * 32];
        #pragma unroll
        for (int i = 0; i < 4; i++) dst[i] = src[i];
    }
    __syncthreads();
    s8v bj[4][4];
    #pragma unroll
    for (int ct = 0; ct < 4; ct++)
        #pragma unroll
        for (int ks = 0; ks < 4; ks++)
            bj[ct][ks] = *(const s8v*)&Qks[ct*16 + m][q*8 + ks*32];
    f4v accL[2][4];
    #pragma unroll
    for (int mt = 0; mt < 2; mt++)
        #pragma unroll
        for (int ct = 0; ct < 4; ct++){ f4v z = {0.f,0.f,0.f,0.f}; accL[mt][ct] = z; }
    const float scale = 0.015625f;
    for (int kt = 0; kt < 16; kt++){
        int k0 = kbase + kt*64;
        __syncthreads();
        {
            int r = t >> 2, ch = t & 3;
            const uint4* src = (const uint4*)(QTb + (long long)(k0 + r) * CO + ch * 32);
            uint4* dst = (uint4*)&Qks[r][ch * 32];
            #pragma unroll
            for (int i = 0; i < 4; i++) dst[i] = src[i];
        }
        {
            int c = t >> 1, hf = t & 1;
            const uint4* src = (const uint4*)(Pbb + (long long)c * HW + k0 + hf * 32);
            uint4* dst = (uint4*)&Pcs[c][hf * 32];
            #pragma unroll
            for (int i = 0; i < 4; i++) dst[i] = src[i];
        }
        __syncthreads();
        s8v aS[4];
        #pragma unroll
        for (int ks = 0; ks < 4; ks++) aS[ks] = *(const s8v*)&Qks[w*16 + m][q*8 + ks*32];
        float il[4];
        #pragma unroll
        for (int r = 0; r < 4; r++) il[r] = Il[kt*64 + w*16 + q*4 + r];
        #pragma unroll
        for (int ct = 0; ct < 4; ct++){
            f4v s = {0.f,0.f,0.f,0.f};
            #pragma unroll
            for (int ks = 0; ks < 4; ks++)
                s = __builtin_amdgcn_mfma_f32_16x16x32_bf16(aS[ks], bj[ct][ks], s, 0, 0, 0);
            s4v e4;
            #pragma unroll
            for (int r = 0; r < 4; r++)
                e4[r] = (short)f2bf(__expf(s[r]*scale) * il[r]);
            *(s4v*)&Et[ct*16 + m][w*16 + q*4] = e4;
        }
        __syncthreads();
        s8v aP[2][2];
        #pragma unroll
        for (int mt = 0; mt < 2; mt++)
            #pragma unroll
            for (int ks2 = 0; ks2 < 2; ks2++)
                aP[mt][ks2] = *(const s8v*)&Pcs[w*32 + mt*16 + m][q*8 + ks2*32];
        #pragma unroll
        for (int ct = 0; ct < 4; ct++){
            s8v bE0 = *(const s8v*)&Et[ct*16 + m][q*8];
            s8v bE1 = *(const s8v*)&Et[ct*16 + m][q*8 + 32];
            #pragma unroll
            for (int mt = 0; mt < 2; mt++){
                accL[mt][ct] = __builtin_amdgcn_mfma_f32_16x16x32_bf16(aP[mt][0], bE0, accL[mt][ct], 0, 0, 0);
                accL[mt][ct] = __builtin_amdgcn_mfma_f32_16x16x32_bf16(aP[mt][1], bE1, accL[mt][ct], 0, 0, 0);
            }
        }
    }
    float* Lpb = Lp + ((long long)(kc*NB + b) * CO) * HW;
    #pragma unroll
    for (int mt = 0; mt < 2; mt++)
        #pragma unroll
        for (int ct = 0; ct < 4; ct++)
            #pragma unroll
            for (int r = 0; r < 4; r++){
                int c = w*32 + mt*16 + q*4 + r;
                Lpb[(long long)c*HW + j0 + ct*16 + m] = accL[mt][ct][r];
            }
}

// ---------------- fused: O = xa + sum(Lp) -> bf16 B-tile -> conv2 -> out f32 ----------------
__global__ __launch_bounds__(256)
void k_outfused(const unsigned short* __restrict__ A,    // w_c2 [256][128] bf16
                const float* __restrict__ Lp, const float* __restrict__ xa,
                const float* __restrict__ bias, float* __restrict__ out){
    int b = blockIdx.y, j0 = blockIdx.x*32;
    __shared__ unsigned short Bs[32][136];
    __shared__ __align__(16) char pool[256*68*2];   // phase1: Bsf[128][33] f32; phase2: As[256][68] bf16
    int t = threadIdx.x;
    // phase 1: O tile f32 = xa + 4 partials (coalesced c-rows)
    {
        float* Bsf = (float*)pool;
        int c = t>>1, jh = t&1;
        long long base = ((long long)b*CO + c)*HW + j0 + jh*16;
        const long long csz = (long long)NB*CO*HW;
        float v[16];
        #pragma unroll
        for (int r = 0; r < 16; r++) v[r] = xa[base + r];
        #pragma unroll
        for (int pidx = 0; pidx < 4; pidx++){
            const float* src = Lp + pidx*csz + base;
            #pragma unroll
            for (int r = 0; r < 16; r++) v[r] += src[r];
        }
        #pragma unroll
        for (int r = 0; r < 16; r++) Bsf[c*33 + jh*16 + r] = v[r];
    }
    __syncthreads();
    // transpose to bf16 B-tile [j][c]
    {
        const float* Bsf = (const float*)pool;
        int j = t>>3, cs = t&7;
        #pragma unroll
        for (int r = 0; r < 16; r++){
            int c = cs*16 + r;
            Bs[j][c] = f2bf(Bsf[c*33 + j]);
        }
    }
    __syncthreads();
    // phase 2: GEMM M=256 x N=32 x K=128
    unsigned short (*As)[68] = (unsigned short(*)[68])pool;
    int w = t>>6, lane = t&63, m = lane&15, q = lane>>4;
    f4v acc[4][2];
    #pragma unroll
    for (int ms = 0; ms < 4; ms++)
        #pragma unroll
        for (int ct = 0; ct < 2; ct++){ f4v z = {0.f,0.f,0.f,0.f}; acc[ms][ct] = z; }
    for (int k0 = 0; k0 < 128; k0 += 64){
        __syncthreads();
        {   const uint4* src = (const uint4*)(A + (long long)t*128 + k0);
            uint4* dst = (uint4*)&As[t][0];
            #pragma unroll
            for (int i = 0; i < 8; i++) dst[i] = src[i];
        }
        __syncthreads();
        #pragma unroll
        for (int ks = 0; ks < 2; ks++){
            s8v bfr[2];
            #pragma unroll
            for (int ct = 0; ct < 2; ct++) bfr[ct] = *(const s8v*)&Bs[ct*16+m][k0 + ks*32 + q*8];
            #pragma unroll
            for (int ms = 0; ms < 4; ms++){
                s8v afr = *(const s8v*)&As[w*64 + ms*16 + m][q*8 + ks*32];
                #pragma unroll
                for (int ct = 0; ct < 2; ct++)
                    acc[ms][ct] = __builtin_amdgcn_mfma_f32_16x16x32_bf16(afr, bfr[ct], acc[ms][ct], 0,0,0);
            }
        }
    }
    #pragma unroll
    for (int ct = 0; ct < 2; ct++){
        int p = j0 + ct*16 + m;
        #pragma unroll
        for (int ms = 0; ms < 4; ms++)
            #pragma unroll
            for (int r = 0; r < 4; r++){
                int c = w*64 + ms*16 + q*4 + r;
                out[((long long)b*256 + c)*HW + p] = acc[ms][ct][r] + bias[c];
            }
    }
}

extern "C" void kernel_launch(void* const* d_in, const int* in_sizes, int n_in,
                              void* d_out, int out_size, void* d_ws, size_t ws_size,
                              hipStream_t stream) {
    const float* x       = (const float*)d_in[0];
    const float* conv1_w = (const float*)d_in[1];
    const float* conv1_b = (const float*)d_in[2];
    const float* conv2_w = (const float*)d_in[3];
    const float* conv2_b = (const float*)d_in[4];
    const float* cw_w1   = (const float*)d_in[5];
    const float* cw_b1   = (const float*)d_in[6];
    const float* cw_g    = (const float*)d_in[7];
    const float* cw_bt   = (const float*)d_in[8];
    const float* cw_w2   = (const float*)d_in[9];
    const float* cw_b2   = (const float*)d_in[10];
    const float* a0_w    = (const float*)d_in[11];
    const float* a0_g    = (const float*)d_in[12];
    const float* a0_b    = (const float*)d_in[13];
    const float* a1_w    = (const float*)d_in[14];
    const float* a1_g    = (const float*)d_in[15];
    const float* a1_b    = (const float*)d_in[16];
    const float* a2_w    = (const float*)d_in[17];
    const float* a2_g    = (const float*)d_in[18];
    const float* a2_b    = (const float*)d_in[19];
    const float* a3_w    = (const float*)d_in[20];
    const float* a3_g    = (const float*)d_in[21];
    const float* a3_b    = (const float*)d_in[22];
    const float* ap_w    = (const float*)d_in[23];
    const float* ap_g    = (const float*)d_in[24];
    const float* ap_b    = (const float*)d_in[25];
    const float* pj_w    = (const float*)d_in[26];
    const float* pj_g    = (const float*)d_in[27];
    const float* pj_b    = (const float*)d_in[28];
    float* out = (float*)d_out;

    // ---- workspace layout ----
    float* ws    = (float*)d_ws;
    float* avg   = ws;                  // 1024
    float* mx    = ws + 1024;           // 1024
    float* sv    = ws + 2048;           // 1024
    float* gp    = ws + 3072;           // 1024
    float* xa    = ws + 37888;          // 2,097,152
    float* lpart = xa + 2097152;        // 65536
    unsigned short* sb = (unsigned short*)(ws + 4232192);
    unsigned short* xT    = sb;                    // 4,194,304
    unsigned short* xcT   = sb + 4194304;          // 4,194,304
    unsigned short* catT  = sb + 8388608;          // 20,971,520
    unsigned short* projT = sb + 29360128;         // 4,194,304
    unsigned short* P_bf  = sb + 33554432;         // 2,097,152
    unsigned short* PT_bf = sb + 35651584;         // 2,097,152
    unsigned short* QT_bf = sb + 37748736;         // 2,097,152
    unsigned short* w_c1  = sb + 41943040;         // 32768
    unsigned short* w_a0  = sb + 41975808;         // 65536
    unsigned short* w_pj  = sb + 42041344;         // 327680
    unsigned short* w_c2  = sb + 42369024;         // 32768
    unsigned short* w_d3  = sb + 42401792;         // 589824
    unsigned short* w_d6  = sb + 42991616;         // 589824
    unsigned short* w_d9  = sb + 43581440;         // 589824
    float* Lp = (float*)catT;           // alias: catT dead after proj (33.5MB in 42MB region)

    // ---- rowstats + all weight casts (one launch) ----
    k_pre<<<dim3(9728), 256, 0, stream>>>(x, avg, mx,
                                          conv1_w, a0_w, pj_w, conv2_w, a1_w, a2_w, a3_w,
                                          w_c1, w_a0, w_pj, w_c2, w_d3, w_d6, w_d9);
    k_cw<<<dim3(NB), 256, 0, stream>>>(avg, mx, cw_w1, cw_b1, cw_g, cw_bt, cw_w2, cw_b2, sv, gp);

    // ---- x -> xT bf16 and xcT ----
    k_xT<<<dim3(64, 4, NB), 256, 0, stream>>>(x, sv, xT, xcT);

    // ---- x1 = conv1(x)+b -> P_bf/PT_bf ----
    k_conv1m<<<dim3(128, NB), 256, 0, stream>>>(w_c1, xT, conv1_b, PT_bf, P_bf, nullptr);

    // ---- ASPP: a0 + 3 dilated convs + pool/bcast in ONE launch ----
    k_aspp<<<dim3(128, 5, NB), 512, 0, stream>>>(w_a0, w_d3, w_d6, w_d9, xcT,
                                                 a0_g, a0_b, a1_g, a1_b, a2_g, a2_b, a3_g, a3_b,
                                                 gp, ap_w, ap_g, ap_b, catT);

    // ---- proj = GELU(LN(conv1x1(cat))) -> projT bf16 ----
    k_branch1<<<dim3(128, NB), 512, 0, stream>>>(w_pj, 1280, catT, pj_g, pj_b, projT, 256, 0);

    // ---- xa = conv1(proj)+b -> xa f32 + QT_bf ----
    k_conv1m<<<dim3(128, NB), 256, 0, stream>>>(w_c1, projT, conv1_b, QT_bf, nullptr, xa);

    // ---- attention (no-max softmax; comb fused into apply) ----
    k_attn_stats3<<<dim3(32, 4, NB), 256, 0, stream>>>(QT_bf, PT_bf, lpart);
    k_attn_apply2<<<dim3(64, 4, NB), 256, 0, stream>>>(QT_bf, PT_bf, P_bf, lpart, Lp);

    // ---- out = conv2(xa + sum Lp) + b (fused) ----
    k_outfused<<<dim3(128, NB), 256, 0, stream>>>(w_c2, Lp, xa, conv2_b, out);

    (void)in_sizes; (void)n_in; (void)out_size; (void)ws_size;
}